// Round 1
// baseline (678.291 us; speedup 1.0000x reference)
//
#include <hip/hip_runtime.h>

// ---------------- problem constants ----------------
#define S_LEN 2048
#define HD    4096
#define NH    32
#define NKV   8
#define DH    128

typedef __bf16 bf16_t;
typedef __bf16 bf16x8 __attribute__((ext_vector_type(8)));
typedef __bf16 bf16x4v __attribute__((ext_vector_type(4)));
typedef float  f32x4  __attribute__((ext_vector_type(4)));

// ---------------- helpers ----------------
__device__ inline unsigned short f2bf_bits(float f) {
  unsigned int u = __builtin_bit_cast(unsigned int, f);
  unsigned int r = (u + 0x7FFFu + ((u >> 16) & 1u)) >> 16;  // RNE
  return (unsigned short)r;
}
__device__ inline bf16_t f2bf(float f) {
  return __builtin_bit_cast(bf16_t, f2bf_bits(f));
}
__device__ inline float bf2f(bf16_t b) {
  unsigned int u = ((unsigned int)__builtin_bit_cast(unsigned short, b)) << 16;
  return __builtin_bit_cast(float, u);
}

__device__ inline void load_lds16(const void* g, void* l) {
  __builtin_amdgcn_global_load_lds(
      (__attribute__((address_space(1))) unsigned int*)(void*)g,
      (__attribute__((address_space(3))) unsigned int*)l, 16, 0, 0);
}

__device__ inline void store_out(float* p, float v)  { *p = v; }
__device__ inline void store_out(bf16_t* p, float v) { *p = f2bf(v); }

// ---------------- f32 -> bf16 convert (vectorized) ----------------
__global__ void cvt_kernel(const float* __restrict__ in, bf16_t* __restrict__ out, int n4) {
  int i = blockIdx.x * blockDim.x + threadIdx.x;
  if (i >= n4) return;
  float4 v = reinterpret_cast<const float4*>(in)[i];
  ushort4 o;
  o.x = f2bf_bits(v.x);
  o.y = f2bf_bits(v.y);
  o.z = f2bf_bits(v.z);
  o.w = f2bf_bits(v.w);
  reinterpret_cast<ushort4*>(out)[i] = o;
}

// ---------------- GEMM: C[M,N] = A[M,K] * B[N,K]^T  (m97 structure) ----------------
// 128x128 tile, BK=32, 256 threads (2x2 waves of 64x64), global_load_lds width 16.
template <typename OutT>
__global__ __launch_bounds__(256)
void gemm_bt_kernel(const bf16_t* __restrict__ A, const bf16_t* __restrict__ B,
                    OutT* __restrict__ C, int M, int N, int K) {
  __shared__ __align__(16) bf16_t lA[128 * 32];
  __shared__ __align__(16) bf16_t lB[128 * 32];
  const int t = threadIdx.x;
  const int lane = t & 63, wave = t >> 6;
  const int row0 = blockIdx.y * 128, col0 = blockIdx.x * 128;
  const int wm = (wave >> 1) * 64, wn = (wave & 1) * 64;

  // staging: thread handles two 16B chunks of each tile.
  // chunk byte offset o = wave*2048 + lane*16 (+1024); row = o/64, colbyte = o%64
  const int rA = wave * 32 + (lane >> 2);
  const int cA = (lane & 3) * 8;
  const char* Asrc0 = (const char*)(A + (size_t)(row0 + rA) * K + cA);
  const char* Asrc1 = (const char*)(A + (size_t)(row0 + rA + 16) * K + cA);
  const char* Bsrc0 = (const char*)(B + (size_t)(col0 + rA) * K + cA);
  const char* Bsrc1 = (const char*)(B + (size_t)(col0 + rA + 16) * K + cA);
  char* lAd = (char*)lA + wave * 2048;
  char* lBd = (char*)lB + wave * 2048;

  f32x4 acc[4][4] = {};
  const int fr = lane & 15, fq = lane >> 4;

  for (int k0 = 0; k0 < K; k0 += 32) {
    const size_t kb = (size_t)k0 * 2;
    load_lds16(Asrc0 + kb, lAd);
    load_lds16(Asrc1 + kb, lAd + 1024);
    load_lds16(Bsrc0 + kb, lBd);
    load_lds16(Bsrc1 + kb, lBd + 1024);
    __syncthreads();
    bf16x8 af[4], bfv[4];
#pragma unroll
    for (int mi = 0; mi < 4; mi++)
      af[mi] = *reinterpret_cast<const bf16x8*>(&lA[(wm + mi * 16 + fr) * 32 + fq * 8]);
#pragma unroll
    for (int ni = 0; ni < 4; ni++)
      bfv[ni] = *reinterpret_cast<const bf16x8*>(&lB[(wn + ni * 16 + fr) * 32 + fq * 8]);
#pragma unroll
    for (int mi = 0; mi < 4; mi++)
#pragma unroll
      for (int ni = 0; ni < 4; ni++)
        acc[mi][ni] = __builtin_amdgcn_mfma_f32_16x16x32_bf16(af[mi], bfv[ni], acc[mi][ni], 0, 0, 0);
    __syncthreads();
  }

#pragma unroll
  for (int mi = 0; mi < 4; mi++) {
#pragma unroll
    for (int r = 0; r < 4; r++) {
      int row = row0 + wm + mi * 16 + fq * 4 + r;
      OutT* Cp = C + (size_t)row * N + col0 + wn + fr;
#pragma unroll
      for (int ni = 0; ni < 4; ni++) store_out(Cp + ni * 16, acc[mi][ni][r]);
    }
  }
}

// ---------------- RoPE (in place), folds score scale into Q ----------------
__global__ void rope_kernel(bf16_t* __restrict__ x, int heads, float scale) {
  int idx = blockIdx.x * blockDim.x + threadIdx.x;  // total = S*heads*64
  int i = idx & 63;
  int h = (idx >> 6) % heads;
  int s = idx / (64 * heads);
  const float NEG_LOG1E4_64 = -0.14391156f;  // -ln(10000)/64
  float freq = __expf((float)i * NEG_LOG1E4_64);
  float ang = (float)s * freq;
  float sn, cs;
  __sincosf(ang, &sn, &cs);
  bf16_t* p = x + ((size_t)s * heads + h) * DH;
  float x1 = bf2f(p[i]);
  float x2 = bf2f(p[i + 64]);
  p[i]      = f2bf((x1 * cs - x2 * sn) * scale);
  p[i + 64] = f2bf((x2 * cs + x1 * sn) * scale);
}

// ---------------- transpose [R][C] -> [C][R] (bf16), 64x64 LDS tiles ----------------
__global__ void transpose_kernel(const bf16_t* __restrict__ in, bf16_t* __restrict__ out,
                                 int R, int C) {
  __shared__ bf16_t tile[64][65];
  int c0 = blockIdx.x * 64, r0 = blockIdx.y * 64;
  int t = threadIdx.x;
#pragma unroll
  for (int i = 0; i < 16; i++) {
    int idx = t + i * 256;
    int r = idx >> 6, c = idx & 63;
    tile[r][c] = in[(size_t)(r0 + r) * C + c0 + c];
  }
  __syncthreads();
#pragma unroll
  for (int i = 0; i < 16; i++) {
    int idx = t + i * 256;
    int r = idx >> 6, c = idx & 63;
    out[(size_t)(c0 + r) * R + r0 + c] = tile[c][r];
  }
}

// ---------------- flash attention (causal, GQA) ----------------
// grid (S/64, NH); 256 threads = 4 waves; wave w owns rows qb*64 + w*16 .. +15.
// K tile [32 kv][128 d] in LDS, XOR-swizzled (byte ^ (kvrow&7)<<4) via pre-swizzled
// global source (rule #21). V^T tile [128 d][32 kv], swizzled (byte ^ (d&3)<<4).
__global__ __launch_bounds__(256)
void attn_kernel(const bf16_t* __restrict__ Q, const bf16_t* __restrict__ K,
                 const bf16_t* __restrict__ Vt, bf16_t* __restrict__ O) {
  __shared__ __align__(16) char lK[32 * 256];   // 8 KB
  __shared__ __align__(16) char lV[128 * 64];   // 8 KB
  __shared__ __align__(16) bf16_t lP[4][16 * 36];  // stride 36 to spread banks

  const int t = threadIdx.x, lane = t & 63, wave = t >> 6;
  const int h = blockIdx.y, kvh = h >> 2;
  const int q0b = blockIdx.x * 64;
  const int q0 = q0b + wave * 16;
  const int fr = lane & 15, fq = lane >> 4;

  // Q fragments (held in registers for the whole kernel)
  bf16x8 qf[4];
  const bf16_t* Qp = Q + ((size_t)(q0 + fr) * NH + h) * DH + fq * 8;
#pragma unroll
  for (int kt = 0; kt < 4; kt++)
    qf[kt] = *reinterpret_cast<const bf16x8*>(Qp + kt * 32);

  f32x4 o_acc[8] = {};
  float m_run[4] = {-1e30f, -1e30f, -1e30f, -1e30f};
  float l_run[4] = {0.f, 0.f, 0.f, 0.f};

  // staging geometry (two 16B chunks per thread per tile)
  const int oK = wave * 2048 + lane * 16;
  const int rK0 = oK >> 8, cbK0 = oK & 255;
  const int rK1 = (oK + 1024) >> 8, cbK1 = (oK + 1024) & 255;
  const int dV0 = oK >> 6, kbV0 = oK & 63;
  const int dV1 = (oK + 1024) >> 6, kbV1 = (oK + 1024) & 63;
  const char* Kbase = (const char*)K + (size_t)kvh * 256;           // + kv*2048B + dbyte
  const char* Vbase = (const char*)Vt + (size_t)kvh * DH * S_LEN * 2;  // + d*4096B + sbyte
  char* lKd = lK + wave * 2048;
  char* lVd = lV + wave * 2048;

  const int kv_end = q0b + 64;
  for (int kv0 = 0; kv0 < kv_end; kv0 += 32) {
    load_lds16(Kbase + (size_t)(kv0 + rK0) * 2048 + (cbK0 ^ ((rK0 & 7) << 4)), lKd);
    load_lds16(Kbase + (size_t)(kv0 + rK1) * 2048 + (cbK1 ^ ((rK1 & 7) << 4)), lKd + 1024);
    load_lds16(Vbase + (size_t)dV0 * 4096 + kv0 * 2 + (kbV0 ^ ((dV0 & 3) << 4)), lVd);
    load_lds16(Vbase + (size_t)dV1 * 4096 + kv0 * 2 + (kbV1 ^ ((dV1 & 3) << 4)), lVd + 1024);
    __syncthreads();

    if (kv0 <= q0 + 15) {  // wave-uniform: tile not fully above the diagonal
      // ---- S = Q K^T ----
      f32x4 s_acc[2] = {};
#pragma unroll
      for (int nt = 0; nt < 2; nt++) {
        int krow = nt * 16 + fr;
#pragma unroll
        for (int kt = 0; kt < 4; kt++) {
          const bf16x8 kf = *reinterpret_cast<const bf16x8*>(
              lK + krow * 256 + ((kt * 64 + fq * 16) ^ ((krow & 7) << 4)));
          s_acc[nt] = __builtin_amdgcn_mfma_f32_16x16x32_bf16(qf[kt], kf, s_acc[nt], 0, 0, 0);
        }
      }
      // ---- online softmax (rows owned: q0 + fq*4 + r; cols: kv0 + nt*16 + fr) ----
      bf16_t* lPw = lP[wave];
#pragma unroll
      for (int r = 0; r < 4; r++) {
        int qrow = q0 + fq * 4 + r;
        float s0 = s_acc[0][r], s1 = s_acc[1][r];
        if (kv0 + fr > qrow) s0 = -1e30f;
        if (kv0 + 16 + fr > qrow) s1 = -1e30f;
        float mr = fmaxf(s0, s1);
#pragma unroll
        for (int off = 1; off < 16; off <<= 1) mr = fmaxf(mr, __shfl_xor(mr, off, 16));
        float mnew = fmaxf(m_run[r], mr);
        float alpha = __expf(m_run[r] - mnew);
        m_run[r] = mnew;
        float p0 = __expf(s0 - mnew), p1 = __expf(s1 - mnew);
        float sr = p0 + p1;
#pragma unroll
        for (int off = 1; off < 16; off <<= 1) sr += __shfl_xor(sr, off, 16);
        l_run[r] = l_run[r] * alpha + sr;
#pragma unroll
        for (int ni = 0; ni < 8; ni++) o_acc[ni][r] *= alpha;
        lPw[(fq * 4 + r) * 36 + fr]      = f2bf(p0);
        lPw[(fq * 4 + r) * 36 + 16 + fr] = f2bf(p1);
      }
      // ---- P fragment (A-operand layout) ----
      bf16x4v pl0 = *reinterpret_cast<const bf16x4v*>(&lPw[fr * 36 + fq * 8]);
      bf16x4v pl1 = *reinterpret_cast<const bf16x4v*>(&lPw[fr * 36 + fq * 8 + 4]);
      bf16x8 pf;
      pf[0] = pl0[0]; pf[1] = pl0[1]; pf[2] = pl0[2]; pf[3] = pl0[3];
      pf[4] = pl1[0]; pf[5] = pl1[1]; pf[6] = pl1[2]; pf[7] = pl1[3];
      // ---- O += P V ----
#pragma unroll
      for (int ni = 0; ni < 8; ni++) {
        int d = ni * 16 + fr;
        const bf16x8 vf = *reinterpret_cast<const bf16x8*>(
            lV + d * 64 + ((fq * 16) ^ ((d & 3) << 4)));
        o_acc[ni] = __builtin_amdgcn_mfma_f32_16x16x32_bf16(pf, vf, o_acc[ni], 0, 0, 0);
      }
    }
    __syncthreads();
  }

  // ---- epilogue: normalize and store ----
#pragma unroll
  for (int r = 0; r < 4; r++) {
    int qrow = q0 + fq * 4 + r;
    float inv = 1.0f / l_run[r];
    bf16_t* Op = O + ((size_t)qrow * NH + h) * DH + fr;
#pragma unroll
    for (int ni = 0; ni < 8; ni++) Op[ni * 16] = f2bf(o_acc[ni][r] * inv);
  }
}

// ---------------- launch ----------------
extern "C" void kernel_launch(void* const* d_in, const int* in_sizes, int n_in,
                              void* d_out, int out_size, void* d_ws, size_t ws_size,
                              hipStream_t stream) {
  const float* X  = (const float*)d_in[0];
  const float* Wq = (const float*)d_in[1];
  const float* Wk = (const float*)d_in[2];
  const float* Wv = (const float*)d_in[3];
  const float* Wo = (const float*)d_in[4];
  float* out = (float*)d_out;

  char* ws = (char*)d_ws;
  size_t off = 0;
  auto alloc = [&](size_t bytes) {
    char* p = ws + off;
    off += (bytes + 255) & ~(size_t)255;
    return p;
  };
  const size_t kvdim = (size_t)NKV * DH;           // 1024
  bf16_t* Xb  = (bf16_t*)alloc((size_t)S_LEN * HD * 2);
  bf16_t* Wqb = (bf16_t*)alloc((size_t)HD * HD * 2);
  bf16_t* Wkb = (bf16_t*)alloc(kvdim * HD * 2);
  bf16_t* Wvb = (bf16_t*)alloc(kvdim * HD * 2);
  bf16_t* Wob = (bf16_t*)alloc((size_t)HD * HD * 2);
  bf16_t* Qb  = (bf16_t*)alloc((size_t)S_LEN * HD * 2);
  bf16_t* Kb  = (bf16_t*)alloc((size_t)S_LEN * kvdim * 2);
  bf16_t* Vb  = (bf16_t*)alloc((size_t)S_LEN * kvdim * 2);
  bf16_t* Vtb = (bf16_t*)alloc((size_t)S_LEN * kvdim * 2);
  bf16_t* AOb = (bf16_t*)alloc((size_t)S_LEN * HD * 2);
  (void)ws_size;

  auto cvt = [&](const float* in, bf16_t* o, size_t n) {
    int n4 = (int)(n / 4);
    cvt_kernel<<<dim3((n4 + 255) / 256), dim3(256), 0, stream>>>(in, o, n4);
  };
  cvt(X,  Xb,  (size_t)S_LEN * HD);
  cvt(Wq, Wqb, (size_t)HD * HD);
  cvt(Wk, Wkb, kvdim * HD);
  cvt(Wv, Wvb, kvdim * HD);
  cvt(Wo, Wob, (size_t)HD * HD);

  // projections
  gemm_bt_kernel<bf16_t><<<dim3(HD / 128, S_LEN / 128), dim3(256), 0, stream>>>(
      Xb, Wqb, Qb, S_LEN, HD, HD);
  gemm_bt_kernel<bf16_t><<<dim3((int)kvdim / 128, S_LEN / 128), dim3(256), 0, stream>>>(
      Xb, Wkb, Kb, S_LEN, (int)kvdim, HD);
  gemm_bt_kernel<bf16_t><<<dim3((int)kvdim / 128, S_LEN / 128), dim3(256), 0, stream>>>(
      Xb, Wvb, Vb, S_LEN, (int)kvdim, HD);

  // RoPE (scale 1/sqrt(128) folded into Q)
  rope_kernel<<<dim3(S_LEN * NH * 64 / 256), dim3(256), 0, stream>>>(
      Qb, NH, 0.08838834764831845f);
  rope_kernel<<<dim3(S_LEN * NKV * 64 / 256), dim3(256), 0, stream>>>(Kb, NKV, 1.0f);

  // V^T for clean PV staging
  transpose_kernel<<<dim3((int)kvdim / 64, S_LEN / 64), dim3(256), 0, stream>>>(
      Vb, Vtb, S_LEN, (int)kvdim);

  // attention
  attn_kernel<<<dim3(S_LEN / 64, NH), dim3(256), 0, stream>>>(Qb, Kb, Vtb, AOb);

  // output projection (f32 out)
  gemm_bt_kernel<float><<<dim3(HD / 128, S_LEN / 128), dim3(256), 0, stream>>>(
      AOb, Wob, out, S_LEN, HD, HD);
}

// Round 2
// 612.555 us; speedup vs baseline: 1.1073x; 1.1073x over previous
//
#include <hip/hip_runtime.h>

// ---------------- problem constants ----------------
#define S_LEN 2048
#define HD    4096
#define NH    32
#define NKV   8
#define DH    128

typedef __bf16 bf16_t;
typedef __bf16 bf16x8 __attribute__((ext_vector_type(8)));
typedef float  f32x4  __attribute__((ext_vector_type(4)));

// ---------------- helpers ----------------
__device__ inline unsigned short f2bf_bits(float f) {
  unsigned int u = __builtin_bit_cast(unsigned int, f);
  unsigned int r = (u + 0x7FFFu + ((u >> 16) & 1u)) >> 16;  // RNE
  return (unsigned short)r;
}
__device__ inline bf16_t f2bf(float f) {
  return __builtin_bit_cast(bf16_t, f2bf_bits(f));
}
__device__ inline float bf2f(bf16_t b) {
  unsigned int u = ((unsigned int)__builtin_bit_cast(unsigned short, b)) << 16;
  return __builtin_bit_cast(float, u);
}

__device__ inline void load_lds16(const void* g, void* l) {
  __builtin_amdgcn_global_load_lds(
      (__attribute__((address_space(1))) unsigned int*)(void*)g,
      (__attribute__((address_space(3))) unsigned int*)l, 16, 0, 0);
}

__device__ inline void store_out(float* p, float v)  { *p = v; }
__device__ inline void store_out(bf16_t* p, float v) { *p = f2bf(v); }

// ---------------- f32 -> bf16 convert (vectorized) ----------------
__global__ void cvt_kernel(const float* __restrict__ in, bf16_t* __restrict__ out, int n4) {
  int i = blockIdx.x * blockDim.x + threadIdx.x;
  if (i >= n4) return;
  float4 v = reinterpret_cast<const float4*>(in)[i];
  ushort4 o;
  o.x = f2bf_bits(v.x);
  o.y = f2bf_bits(v.y);
  o.z = f2bf_bits(v.z);
  o.w = f2bf_bits(v.w);
  reinterpret_cast<ushort4*>(out)[i] = o;
}

// ---------------- GEMM: C[M,N] = A[M,K] * B[N,K]^T  (m97 structure) ----------------
template <typename OutT>
__global__ __launch_bounds__(256)
void gemm_bt_kernel(const bf16_t* __restrict__ A, const bf16_t* __restrict__ B,
                    OutT* __restrict__ C, int M, int N, int K) {
  __shared__ __align__(16) bf16_t lA[128 * 32];
  __shared__ __align__(16) bf16_t lB[128 * 32];
  const int t = threadIdx.x;
  const int lane = t & 63, wave = t >> 6;
  const int row0 = blockIdx.y * 128, col0 = blockIdx.x * 128;
  const int wm = (wave >> 1) * 64, wn = (wave & 1) * 64;

  const int rA = wave * 32 + (lane >> 2);
  const int cA = (lane & 3) * 8;
  const char* Asrc0 = (const char*)(A + (size_t)(row0 + rA) * K + cA);
  const char* Asrc1 = (const char*)(A + (size_t)(row0 + rA + 16) * K + cA);
  const char* Bsrc0 = (const char*)(B + (size_t)(col0 + rA) * K + cA);
  const char* Bsrc1 = (const char*)(B + (size_t)(col0 + rA + 16) * K + cA);
  char* lAd = (char*)lA + wave * 2048;
  char* lBd = (char*)lB + wave * 2048;

  f32x4 acc[4][4] = {};
  const int fr = lane & 15, fq = lane >> 4;

  for (int k0 = 0; k0 < K; k0 += 32) {
    const size_t kb = (size_t)k0 * 2;
    load_lds16(Asrc0 + kb, lAd);
    load_lds16(Asrc1 + kb, lAd + 1024);
    load_lds16(Bsrc0 + kb, lBd);
    load_lds16(Bsrc1 + kb, lBd + 1024);
    __syncthreads();
    bf16x8 af[4], bfv[4];
#pragma unroll
    for (int mi = 0; mi < 4; mi++)
      af[mi] = *reinterpret_cast<const bf16x8*>(&lA[(wm + mi * 16 + fr) * 32 + fq * 8]);
#pragma unroll
    for (int ni = 0; ni < 4; ni++)
      bfv[ni] = *reinterpret_cast<const bf16x8*>(&lB[(wn + ni * 16 + fr) * 32 + fq * 8]);
#pragma unroll
    for (int mi = 0; mi < 4; mi++)
#pragma unroll
      for (int ni = 0; ni < 4; ni++)
        acc[mi][ni] = __builtin_amdgcn_mfma_f32_16x16x32_bf16(af[mi], bfv[ni], acc[mi][ni], 0, 0, 0);
    __syncthreads();
  }

#pragma unroll
  for (int mi = 0; mi < 4; mi++) {
#pragma unroll
    for (int r = 0; r < 4; r++) {
      int row = row0 + wm + mi * 16 + fq * 4 + r;
      OutT* Cp = C + (size_t)row * N + col0 + wn + fr;
#pragma unroll
      for (int ni = 0; ni < 4; ni++) store_out(Cp + ni * 16, acc[mi][ni][r]);
    }
  }
}

// ---------------- RoPE (in place), folds score scale into Q ----------------
__global__ void rope_kernel(bf16_t* __restrict__ x, int heads, float scale) {
  int idx = blockIdx.x * blockDim.x + threadIdx.x;  // total = S*heads*64
  int i = idx & 63;
  int h = (idx >> 6) % heads;
  int s = idx / (64 * heads);
  const float NEG_LOG1E4_64 = -0.14391156f;  // -ln(10000)/64
  float freq = __expf((float)i * NEG_LOG1E4_64);
  float ang = (float)s * freq;
  float sn, cs;
  __sincosf(ang, &sn, &cs);
  bf16_t* p = x + ((size_t)s * heads + h) * DH;
  float x1 = bf2f(p[i]);
  float x2 = bf2f(p[i + 64]);
  p[i]      = f2bf((x1 * cs - x2 * sn) * scale);
  p[i + 64] = f2bf((x2 * cs + x1 * sn) * scale);
}

// ---------------- transpose [R][C] -> [C][R] (bf16), 64x64 LDS tiles ----------------
__global__ void transpose_kernel(const bf16_t* __restrict__ in, bf16_t* __restrict__ out,
                                 int R, int C) {
  __shared__ bf16_t tile[64][65];
  int c0 = blockIdx.x * 64, r0 = blockIdx.y * 64;
  int t = threadIdx.x;
#pragma unroll
  for (int i = 0; i < 16; i++) {
    int idx = t + i * 256;
    int r = idx >> 6, c = idx & 63;
    tile[r][c] = in[(size_t)(r0 + r) * C + c0 + c];
  }
  __syncthreads();
#pragma unroll
  for (int i = 0; i < 16; i++) {
    int idx = t + i * 256;
    int r = idx >> 6, c = idx & 63;
    out[(size_t)(c0 + r) * R + r0 + c] = tile[c][r];
  }
}

// ---------------- flash attention (causal, GQA) ----------------
// grid (S/64, NH), qb reversed for load balance; 256 threads = 4 waves.
// KVBLK=64, double-buffered K and V tiles, one barrier per tile (2-phase
// pipeline: prefetch t+1 issued right after the barrier, compute t under it).
// K tile: [64 kv][256B], XOR-swizzled slot ^= (row&15) via pre-swizzled source.
// V tile: [64 g][256B] where row g holds d=2g,2g+1 (each 128B), same swizzle.
// P round-trip per wave via lP[16][72].
__global__ __launch_bounds__(256)
void attn_kernel(const bf16_t* __restrict__ Q, const bf16_t* __restrict__ K,
                 const bf16_t* __restrict__ Vt, bf16_t* __restrict__ O) {
  __shared__ __align__(16) char lK[2][64 * 256];   // 16 KB x2
  __shared__ __align__(16) char lV[2][64 * 256];   // 16 KB x2
  __shared__ __align__(16) bf16_t lP[4][16 * 72];  // 9216 B

  const int t = threadIdx.x, lane = t & 63, wave = t >> 6;
  const int h = blockIdx.y, kvh = h >> 2;
  const int qb = gridDim.x - 1 - blockIdx.x;       // reversed: long blocks first
  const int q0b = qb * 64;
  const int q0 = q0b + wave * 16;
  const int fr = lane & 15, fq = lane >> 4;

  // Q fragments (registers for whole kernel)
  bf16x8 qf[4];
  const bf16_t* Qp = Q + ((size_t)(q0 + fr) * NH + h) * DH + fq * 8;
#pragma unroll
  for (int kt = 0; kt < 4; kt++)
    qf[kt] = *reinterpret_cast<const bf16x8*>(Qp + kt * 32);

  f32x4 o_acc[8] = {};
  float m_run[4] = {-1e30f, -1e30f, -1e30f, -1e30f};
  float l_run[4] = {0.f, 0.f, 0.f, 0.f};

  // ---- staging constants (per-thread) ----
  // chunk i: LDS linear offset o = wave*1024 + lane*16 + i*4096; row g = o>>8;
  // dest slot = lane&15; source slot = dest ^ (g&15)  (involution swizzle)
  const int gc = wave * 4 + (lane >> 4);           // + i*16 per chunk
  const int sS = (lane & 15) ^ (gc & 15);          // source slot (per-thread const)
  const char* KsrcB = (const char*)K + (size_t)kvh * 256 +
                      (size_t)gc * 2048 + sS * 16;            // + kv0*2048 + i*32768
  const int dVc = gc * 2 + (sS >> 3);              // + i*32 per chunk
  const char* VsrcB = (const char*)Vt + (size_t)kvh * 128 * 4096 +
                      (size_t)dVc * 4096 + (sS & 7) * 16;     // + kv0*2 + i*131072
  char* dKw = (char*)lK[0] + wave * 1024;
  char* dVw = (char*)lV[0] + wave * 1024;

  auto stage = [&](int buf, int kv0) {
    char* dk = dKw + buf * (64 * 256);
    char* dv = dVw + buf * (64 * 256);
    const char* ks = KsrcB + (size_t)kv0 * 2048;
    const char* vs = VsrcB + (size_t)kv0 * 2;
#pragma unroll
    for (int i = 0; i < 4; i++) {
      load_lds16(ks + i * (16 * 2048), dk + i * 4096);
      load_lds16(vs + i * (size_t)(32 * 4096), dv + i * 4096);
    }
  };

  stage(0, 0);
  int buf = 0;

  for (int tt = 0; tt <= qb; tt++) {
    __syncthreads();  // implicit vmcnt(0): prefetch landed; prev compute done
    if (tt < qb) stage(buf ^ 1, (tt + 1) * 64);

    const char* cK = lK[buf];
    const char* cV = lV[buf];
    const int kv0 = tt * 64;
    const bool diag = (tt == qb);

    // ---- S = Q K^T : 16 MFMA ----
    f32x4 s_acc[4] = {};
    __builtin_amdgcn_s_setprio(1);
#pragma unroll
    for (int nt = 0; nt < 4; nt++) {
      const char* rowp = cK + (nt * 16 + fr) * 256;
#pragma unroll
      for (int kt = 0; kt < 4; kt++) {
        const bf16x8 kf = *reinterpret_cast<const bf16x8*>(
            rowp + (((kt * 4 + fq) ^ fr) << 4));
        s_acc[nt] = __builtin_amdgcn_mfma_f32_16x16x32_bf16(qf[kt], kf, s_acc[nt], 0, 0, 0);
      }
    }
    __builtin_amdgcn_s_setprio(0);

    // ---- online softmax, defer-max (THR=8) ----
    float pmax[4];
#pragma unroll
    for (int r = 0; r < 4; r++) {
      if (diag) {
        const int qrel = wave * 16 + fq * 4 + r;  // row - q0b ; col rel = nt*16+fr
#pragma unroll
        for (int nt = 0; nt < 4; nt++)
          if (nt * 16 + fr > qrel) s_acc[nt][r] = -1e30f;
      }
      float mr = fmaxf(fmaxf(s_acc[0][r], s_acc[1][r]), fmaxf(s_acc[2][r], s_acc[3][r]));
#pragma unroll
      for (int off = 1; off < 16; off <<= 1) mr = fmaxf(mr, __shfl_xor(mr, off, 16));
      pmax[r] = mr;
    }
    bool nb = (pmax[0] > m_run[0] + 8.f) || (pmax[1] > m_run[1] + 8.f) ||
              (pmax[2] > m_run[2] + 8.f) || (pmax[3] > m_run[3] + 8.f);
    if (__any(nb)) {
#pragma unroll
      for (int r = 0; r < 4; r++) {
        float mnew = fmaxf(m_run[r], pmax[r]);
        float alpha = __expf(m_run[r] - mnew);
#pragma unroll
        for (int ni = 0; ni < 8; ni++) o_acc[ni][r] *= alpha;
        l_run[r] *= alpha;
        m_run[r] = mnew;
      }
    }
    bf16_t* lPw = lP[wave];
#pragma unroll
    for (int r = 0; r < 4; r++) {
      float p0 = __expf(s_acc[0][r] - m_run[r]);
      float p1 = __expf(s_acc[1][r] - m_run[r]);
      float p2 = __expf(s_acc[2][r] - m_run[r]);
      float p3 = __expf(s_acc[3][r] - m_run[r]);
      float sr = (p0 + p1) + (p2 + p3);
#pragma unroll
      for (int off = 1; off < 16; off <<= 1) sr += __shfl_xor(sr, off, 16);
      l_run[r] += sr;
      const int row = fq * 4 + r;
      lPw[row * 72 + fr]      = f2bf(p0);
      lPw[row * 72 + 16 + fr] = f2bf(p1);
      lPw[row * 72 + 32 + fr] = f2bf(p2);
      lPw[row * 72 + 48 + fr] = f2bf(p3);
    }

    // ---- O += P V : 16 MFMA ----
#pragma unroll
    for (int kk = 0; kk < 2; kk++) {
      const bf16x8 pf = *reinterpret_cast<const bf16x8*>(lPw + fr * 72 + kk * 32 + fq * 8);
      __builtin_amdgcn_s_setprio(1);
#pragma unroll
      for (int ni = 0; ni < 8; ni++) {
        const int d = ni * 16 + fr;
        const int g = d >> 1;
        const int slot = ((d & 1) * 8 + kk * 4 + fq) ^ (g & 15);
        const bf16x8 vf = *reinterpret_cast<const bf16x8*>(cV + g * 256 + (slot << 4));
        o_acc[ni] = __builtin_amdgcn_mfma_f32_16x16x32_bf16(pf, vf, o_acc[ni], 0, 0, 0);
      }
      __builtin_amdgcn_s_setprio(0);
    }
    buf ^= 1;
  }

  // ---- epilogue: normalize and store ----
#pragma unroll
  for (int r = 0; r < 4; r++) {
    int qrow = q0 + fq * 4 + r;
    float inv = 1.0f / l_run[r];
    bf16_t* Op = O + ((size_t)qrow * NH + h) * DH + fr;
#pragma unroll
    for (int ni = 0; ni < 8; ni++) Op[ni * 16] = f2bf(o_acc[ni][r] * inv);
  }
}

// ---------------- launch ----------------
extern "C" void kernel_launch(void* const* d_in, const int* in_sizes, int n_in,
                              void* d_out, int out_size, void* d_ws, size_t ws_size,
                              hipStream_t stream) {
  const float* X  = (const float*)d_in[0];
  const float* Wq = (const float*)d_in[1];
  const float* Wk = (const float*)d_in[2];
  const float* Wv = (const float*)d_in[3];
  const float* Wo = (const float*)d_in[4];
  float* out = (float*)d_out;

  char* ws = (char*)d_ws;
  size_t off = 0;
  auto alloc = [&](size_t bytes) {
    char* p = ws + off;
    off += (bytes + 255) & ~(size_t)255;
    return p;
  };
  const size_t kvdim = (size_t)NKV * DH;           // 1024
  bf16_t* Xb  = (bf16_t*)alloc((size_t)S_LEN * HD * 2);
  bf16_t* Wqb = (bf16_t*)alloc((size_t)HD * HD * 2);
  bf16_t* Wkb = (bf16_t*)alloc(kvdim * HD * 2);
  bf16_t* Wvb = (bf16_t*)alloc(kvdim * HD * 2);
  bf16_t* Wob = (bf16_t*)alloc((size_t)HD * HD * 2);
  bf16_t* Qb  = (bf16_t*)alloc((size_t)S_LEN * HD * 2);
  bf16_t* Kb  = (bf16_t*)alloc((size_t)S_LEN * kvdim * 2);
  bf16_t* Vb  = (bf16_t*)alloc((size_t)S_LEN * kvdim * 2);
  bf16_t* Vtb = (bf16_t*)alloc((size_t)S_LEN * kvdim * 2);
  bf16_t* AOb = (bf16_t*)alloc((size_t)S_LEN * HD * 2);
  (void)ws_size;

  auto cvt = [&](const float* in, bf16_t* o, size_t n) {
    int n4 = (int)(n / 4);
    cvt_kernel<<<dim3((n4 + 255) / 256), dim3(256), 0, stream>>>(in, o, n4);
  };
  cvt(X,  Xb,  (size_t)S_LEN * HD);
  cvt(Wq, Wqb, (size_t)HD * HD);
  cvt(Wk, Wkb, kvdim * HD);
  cvt(Wv, Wvb, kvdim * HD);
  cvt(Wo, Wob, (size_t)HD * HD);

  // projections
  gemm_bt_kernel<bf16_t><<<dim3(HD / 128, S_LEN / 128), dim3(256), 0, stream>>>(
      Xb, Wqb, Qb, S_LEN, HD, HD);
  gemm_bt_kernel<bf16_t><<<dim3((int)kvdim / 128, S_LEN / 128), dim3(256), 0, stream>>>(
      Xb, Wkb, Kb, S_LEN, (int)kvdim, HD);
  gemm_bt_kernel<bf16_t><<<dim3((int)kvdim / 128, S_LEN / 128), dim3(256), 0, stream>>>(
      Xb, Wvb, Vb, S_LEN, (int)kvdim, HD);

  // RoPE (scale 1/sqrt(128) folded into Q)
  rope_kernel<<<dim3(S_LEN * NH * 64 / 256), dim3(256), 0, stream>>>(
      Qb, NH, 0.08838834764831845f);
  rope_kernel<<<dim3(S_LEN * NKV * 64 / 256), dim3(256), 0, stream>>>(Kb, NKV, 1.0f);

  // V^T for clean PV staging
  transpose_kernel<<<dim3((int)kvdim / 64, S_LEN / 64), dim3(256), 0, stream>>>(
      Vb, Vtb, S_LEN, (int)kvdim);

  // attention
  attn_kernel<<<dim3(S_LEN / 64, NH), dim3(256), 0, stream>>>(Qb, Kb, Vtb, AOb);

  // output projection (f32 out)
  gemm_bt_kernel<float><<<dim3(HD / 128, S_LEN / 128), dim3(256), 0, stream>>>(
      AOb, Wob, out, S_LEN, HD, HD);
}

// Round 3
// 593.221 us; speedup vs baseline: 1.1434x; 1.0326x over previous
//
#include <hip/hip_runtime.h>

// ---------------- problem constants ----------------
#define S_LEN 2048
#define HD    4096
#define NH    32
#define NKV   8
#define DH    128
#define NQKV  6144          // 4096 Q + 1024 K + 1024 V
#define QKV_STRIDE_B (NQKV * 2)

typedef __bf16 bf16_t;
typedef __bf16 bf16x8 __attribute__((ext_vector_type(8)));
typedef float  f32x4  __attribute__((ext_vector_type(4)));

// ---------------- helpers ----------------
__device__ inline unsigned short f2bf_bits(float f) {
  unsigned int u = __builtin_bit_cast(unsigned int, f);
  unsigned int r = (u + 0x7FFFu + ((u >> 16) & 1u)) >> 16;  // RNE
  return (unsigned short)r;
}
__device__ inline bf16_t f2bf(float f) {
  return __builtin_bit_cast(bf16_t, f2bf_bits(f));
}
__device__ inline float bf2f(bf16_t b) {
  unsigned int u = ((unsigned int)__builtin_bit_cast(unsigned short, b)) << 16;
  return __builtin_bit_cast(float, u);
}

__device__ inline void load_lds16(const void* g, void* l) {
  __builtin_amdgcn_global_load_lds(
      (__attribute__((address_space(1))) unsigned int*)(void*)g,
      (__attribute__((address_space(3))) unsigned int*)l, 16, 0, 0);
}

__device__ inline void store_out(float* p, float v)  { *p = v; }
__device__ inline void store_out(bf16_t* p, float v) { *p = f2bf(v); }

// ---------------- f32 -> bf16 convert (vectorized) ----------------
__global__ void cvt_kernel(const float* __restrict__ in, bf16_t* __restrict__ out, int n4) {
  int i = blockIdx.x * blockDim.x + threadIdx.x;
  if (i >= n4) return;
  float4 v = reinterpret_cast<const float4*>(in)[i];
  ushort4 o;
  o.x = f2bf_bits(v.x);
  o.y = f2bf_bits(v.y);
  o.z = f2bf_bits(v.z);
  o.w = f2bf_bits(v.w);
  reinterpret_cast<ushort4*>(out)[i] = o;
}

// ---------------- GEMM: C[M,N] = A[M,K] * B[N,K]^T  (m97 structure) ----------------
template <typename OutT>
__global__ __launch_bounds__(256)
void gemm_bt_kernel(const bf16_t* __restrict__ A, const bf16_t* __restrict__ B,
                    OutT* __restrict__ C, int M, int N, int K) {
  __shared__ __align__(16) bf16_t lA[128 * 32];
  __shared__ __align__(16) bf16_t lB[128 * 32];
  const int t = threadIdx.x;
  const int lane = t & 63, wave = t >> 6;
  const int row0 = blockIdx.y * 128, col0 = blockIdx.x * 128;
  const int wm = (wave >> 1) * 64, wn = (wave & 1) * 64;

  const int rA = wave * 32 + (lane >> 2);
  const int cA = (lane & 3) * 8;
  const char* Asrc0 = (const char*)(A + (size_t)(row0 + rA) * K + cA);
  const char* Asrc1 = (const char*)(A + (size_t)(row0 + rA + 16) * K + cA);
  const char* Bsrc0 = (const char*)(B + (size_t)(col0 + rA) * K + cA);
  const char* Bsrc1 = (const char*)(B + (size_t)(col0 + rA + 16) * K + cA);
  char* lAd = (char*)lA + wave * 2048;
  char* lBd = (char*)lB + wave * 2048;

  f32x4 acc[4][4] = {};
  const int fr = lane & 15, fq = lane >> 4;

  for (int k0 = 0; k0 < K; k0 += 32) {
    const size_t kb = (size_t)k0 * 2;
    load_lds16(Asrc0 + kb, lAd);
    load_lds16(Asrc1 + kb, lAd + 1024);
    load_lds16(Bsrc0 + kb, lBd);
    load_lds16(Bsrc1 + kb, lBd + 1024);
    __syncthreads();
    bf16x8 af[4], bfv[4];
#pragma unroll
    for (int mi = 0; mi < 4; mi++)
      af[mi] = *reinterpret_cast<const bf16x8*>(&lA[(wm + mi * 16 + fr) * 32 + fq * 8]);
#pragma unroll
    for (int ni = 0; ni < 4; ni++)
      bfv[ni] = *reinterpret_cast<const bf16x8*>(&lB[(wn + ni * 16 + fr) * 32 + fq * 8]);
#pragma unroll
    for (int mi = 0; mi < 4; mi++)
#pragma unroll
      for (int ni = 0; ni < 4; ni++)
        acc[mi][ni] = __builtin_amdgcn_mfma_f32_16x16x32_bf16(af[mi], bfv[ni], acc[mi][ni], 0, 0, 0);
    __syncthreads();
  }

#pragma unroll
  for (int mi = 0; mi < 4; mi++) {
#pragma unroll
    for (int r = 0; r < 4; r++) {
      int row = row0 + wm + mi * 16 + fq * 4 + r;
      OutT* Cp = C + (size_t)row * N + col0 + wn + fr;
#pragma unroll
      for (int ni = 0; ni < 4; ni++) store_out(Cp + ni * 16, acc[mi][ni][r]);
    }
  }
}

// ---------------- RoPE (in place, strided), folds score scale into Q ----------------
__global__ void rope_kernel(bf16_t* __restrict__ x, int heads, int rstride, float scale) {
  int idx = blockIdx.x * blockDim.x + threadIdx.x;  // total = S*heads*64
  int i = idx & 63;
  int h = (idx >> 6) % heads;
  int s = idx / (64 * heads);
  const float NEG_LOG1E4_64 = -0.14391156f;  // -ln(10000)/64
  float freq = __expf((float)i * NEG_LOG1E4_64);
  float ang = (float)s * freq;
  float sn, cs;
  __sincosf(ang, &sn, &cs);
  bf16_t* p = x + (size_t)s * rstride + h * DH;
  float x1 = bf2f(p[i]);
  float x2 = bf2f(p[i + 64]);
  p[i]      = f2bf((x1 * cs - x2 * sn) * scale);
  p[i + 64] = f2bf((x2 * cs + x1 * sn) * scale);
}

// ---------------- transpose [R][C] -> [C][R] (bf16), strided input ----------------
__global__ void transpose_kernel(const bf16_t* __restrict__ in, bf16_t* __restrict__ out,
                                 int R, int C, int in_rstride) {
  __shared__ bf16_t tile[64][65];
  int c0 = blockIdx.x * 64, r0 = blockIdx.y * 64;
  int t = threadIdx.x;
#pragma unroll
  for (int i = 0; i < 16; i++) {
    int idx = t + i * 256;
    int r = idx >> 6, c = idx & 63;
    tile[r][c] = in[(size_t)(r0 + r) * in_rstride + c0 + c];
  }
  __syncthreads();
#pragma unroll
  for (int i = 0; i < 16; i++) {
    int idx = t + i * 256;
    int r = idx >> 6, c = idx & 63;
    out[(size_t)(c0 + r) * R + r0 + c] = tile[c][r];
  }
}

// ---------------- flash attention (causal, GQA) ----------------
// grid (S/64, NH), qb reversed; 256 threads = 4 waves; KVBLK=64.
// K tile double-buffered in LDS ([64 kv][256B], XOR-swizzled slot ^= row&15 via
// pre-swizzled global source). V fragments read directly from V^T in global
// (per-lane 16B loads, L1/L2-served) -> LDS 42 KB -> 3 blocks/CU.
__global__ __launch_bounds__(256, 3)
void attn_kernel(const bf16_t* __restrict__ Qkv, const bf16_t* __restrict__ Vt,
                 bf16_t* __restrict__ O) {
  __shared__ __align__(16) char lK[2][64 * 256];   // 16 KB x2
  __shared__ __align__(16) bf16_t lP[4][16 * 72];  // 9216 B

  const int t = threadIdx.x, lane = t & 63, wave = t >> 6;
  const int h = blockIdx.y, kvh = h >> 2;
  const int qb = gridDim.x - 1 - blockIdx.x;       // reversed: long blocks first
  const int q0b = qb * 64;
  const int q0 = q0b + wave * 16;
  const int fr = lane & 15, fq = lane >> 4;

  // Q fragments (registers for whole kernel); Q at cols [0,4096) of QKV rows
  bf16x8 qf[4];
  const bf16_t* Qp = Qkv + (size_t)(q0 + fr) * NQKV + h * DH + fq * 8;
#pragma unroll
  for (int kt = 0; kt < 4; kt++)
    qf[kt] = *reinterpret_cast<const bf16x8*>(Qp + kt * 32);

  f32x4 o_acc[8] = {};
  float m_run[4] = {-1e30f, -1e30f, -1e30f, -1e30f};
  float l_run[4] = {0.f, 0.f, 0.f, 0.f};

  // ---- K staging constants ----
  // chunk i: LDS offset o = wave*1024 + lane*16 + i*4096; row g = o>>8 = gc + 16i;
  // dest slot = lane&15; source slot = dest ^ (g&15)
  const int gc = wave * 4 + (lane >> 4);
  const int sS = (lane & 15) ^ (gc & 15);
  const char* KsrcB = (const char*)(Qkv + HD + (size_t)kvh * DH) +
                      (size_t)gc * QKV_STRIDE_B + sS * 16;
  char* dKw = (char*)lK[0] + wave * 1024;

  auto stage = [&](int buf, int kv0) {
    char* dk = dKw + buf * (64 * 256);
    const char* ks = KsrcB + (size_t)kv0 * QKV_STRIDE_B;
#pragma unroll
    for (int i = 0; i < 4; i++)
      load_lds16(ks + i * (16 * QKV_STRIDE_B), dk + i * 4096);
  };

  // V^T rows for this kv head
  const bf16_t* Vrow = Vt + (size_t)kvh * DH * S_LEN;

  stage(0, 0);
  int buf = 0;

  for (int tt = 0; tt <= qb; tt++) {
    __syncthreads();  // implicit vmcnt(0): K prefetch landed; prev compute done
    if (tt < qb) stage(buf ^ 1, (tt + 1) * 64);

    const char* cK = lK[buf];
    const int kv0 = tt * 64;
    const bool diag = (tt == qb);

    // ---- S = Q K^T : 16 MFMA ----
    f32x4 s_acc[4] = {};
    __builtin_amdgcn_s_setprio(1);
#pragma unroll
    for (int nt = 0; nt < 4; nt++) {
      const char* rowp = cK + (nt * 16 + fr) * 256;
#pragma unroll
      for (int kt = 0; kt < 4; kt++) {
        const bf16x8 kf = *reinterpret_cast<const bf16x8*>(
            rowp + (((kt * 4 + fq) ^ fr) << 4));
        s_acc[nt] = __builtin_amdgcn_mfma_f32_16x16x32_bf16(qf[kt], kf, s_acc[nt], 0, 0, 0);
      }
    }
    __builtin_amdgcn_s_setprio(0);

    // ---- prefetch V fragments for kk=0 (per-lane 16B global loads) ----
    bf16x8 vf0[8];
#pragma unroll
    for (int ni = 0; ni < 8; ni++)
      vf0[ni] = *reinterpret_cast<const bf16x8*>(
          Vrow + (size_t)(ni * 16 + fr) * S_LEN + kv0 + fq * 8);

    // ---- online softmax, defer-max (THR=8) ----
    float pmax[4];
#pragma unroll
    for (int r = 0; r < 4; r++) {
      if (diag) {
        const int qrel = wave * 16 + fq * 4 + r;
#pragma unroll
        for (int nt = 0; nt < 4; nt++)
          if (nt * 16 + fr > qrel) s_acc[nt][r] = -1e30f;
      }
      float mr = fmaxf(fmaxf(s_acc[0][r], s_acc[1][r]), fmaxf(s_acc[2][r], s_acc[3][r]));
#pragma unroll
      for (int off = 1; off < 16; off <<= 1) mr = fmaxf(mr, __shfl_xor(mr, off, 16));
      pmax[r] = mr;
    }
    bool nb = (pmax[0] > m_run[0] + 8.f) || (pmax[1] > m_run[1] + 8.f) ||
              (pmax[2] > m_run[2] + 8.f) || (pmax[3] > m_run[3] + 8.f);
    if (__any(nb)) {
#pragma unroll
      for (int r = 0; r < 4; r++) {
        float mnew = fmaxf(m_run[r], pmax[r]);
        float alpha = __expf(m_run[r] - mnew);
#pragma unroll
        for (int ni = 0; ni < 8; ni++) o_acc[ni][r] *= alpha;
        l_run[r] *= alpha;
        m_run[r] = mnew;
      }
    }
    bf16_t* lPw = lP[wave];
#pragma unroll
    for (int r = 0; r < 4; r++) {
      float p0 = __expf(s_acc[0][r] - m_run[r]);
      float p1 = __expf(s_acc[1][r] - m_run[r]);
      float p2 = __expf(s_acc[2][r] - m_run[r]);
      float p3 = __expf(s_acc[3][r] - m_run[r]);
      float sr = (p0 + p1) + (p2 + p3);
#pragma unroll
      for (int off = 1; off < 16; off <<= 1) sr += __shfl_xor(sr, off, 16);
      l_run[r] += sr;
      const int row = fq * 4 + r;
      lPw[row * 72 + fr]      = f2bf(p0);
      lPw[row * 72 + 16 + fr] = f2bf(p1);
      lPw[row * 72 + 32 + fr] = f2bf(p2);
      lPw[row * 72 + 48 + fr] = f2bf(p3);
    }

    // ---- O += P V : 16 MFMA; V for kk=1 prefetched under kk=0's MFMA ----
    const bf16x8 pf0 = *reinterpret_cast<const bf16x8*>(lPw + fr * 72 + fq * 8);
    bf16x8 vf1[8];
#pragma unroll
    for (int ni = 0; ni < 8; ni++)
      vf1[ni] = *reinterpret_cast<const bf16x8*>(
          Vrow + (size_t)(ni * 16 + fr) * S_LEN + kv0 + 32 + fq * 8);
    __builtin_amdgcn_s_setprio(1);
#pragma unroll
    for (int ni = 0; ni < 8; ni++)
      o_acc[ni] = __builtin_amdgcn_mfma_f32_16x16x32_bf16(pf0, vf0[ni], o_acc[ni], 0, 0, 0);
    __builtin_amdgcn_s_setprio(0);
    const bf16x8 pf1 = *reinterpret_cast<const bf16x8*>(lPw + fr * 72 + 32 + fq * 8);
    __builtin_amdgcn_s_setprio(1);
#pragma unroll
    for (int ni = 0; ni < 8; ni++)
      o_acc[ni] = __builtin_amdgcn_mfma_f32_16x16x32_bf16(pf1, vf1[ni], o_acc[ni], 0, 0, 0);
    __builtin_amdgcn_s_setprio(0);
    buf ^= 1;
  }

  // ---- epilogue: normalize and store ----
#pragma unroll
  for (int r = 0; r < 4; r++) {
    int qrow = q0 + fq * 4 + r;
    float inv = 1.0f / l_run[r];
    bf16_t* Op = O + ((size_t)qrow * NH + h) * DH + fr;
#pragma unroll
    for (int ni = 0; ni < 8; ni++) Op[ni * 16] = f2bf(o_acc[ni][r] * inv);
  }
}

// ---------------- launch ----------------
extern "C" void kernel_launch(void* const* d_in, const int* in_sizes, int n_in,
                              void* d_out, int out_size, void* d_ws, size_t ws_size,
                              hipStream_t stream) {
  const float* X  = (const float*)d_in[0];
  const float* Wq = (const float*)d_in[1];
  const float* Wk = (const float*)d_in[2];
  const float* Wv = (const float*)d_in[3];
  const float* Wo = (const float*)d_in[4];
  float* out = (float*)d_out;

  char* ws = (char*)d_ws;
  size_t off = 0;
  auto alloc = [&](size_t bytes) {
    char* p = ws + off;
    off += (bytes + 255) & ~(size_t)255;
    return p;
  };
  const size_t kvdim = (size_t)NKV * DH;           // 1024
  bf16_t* Xb    = (bf16_t*)alloc((size_t)S_LEN * HD * 2);
  bf16_t* Wqkvb = (bf16_t*)alloc((size_t)NQKV * HD * 2);   // [6144][4096]
  bf16_t* Wob   = (bf16_t*)alloc((size_t)HD * HD * 2);
  bf16_t* QKVb  = (bf16_t*)alloc((size_t)S_LEN * NQKV * 2);  // [2048][6144]
  bf16_t* Vtb   = (bf16_t*)alloc((size_t)S_LEN * kvdim * 2); // [1024][2048]
  bf16_t* AOb   = (bf16_t*)alloc((size_t)S_LEN * HD * 2);
  (void)ws_size;

  auto cvt = [&](const float* in, bf16_t* o, size_t n) {
    int n4 = (int)(n / 4);
    cvt_kernel<<<dim3((n4 + 255) / 256), dim3(256), 0, stream>>>(in, o, n4);
  };
  cvt(X,  Xb,    (size_t)S_LEN * HD);
  cvt(Wq, Wqkvb, (size_t)HD * HD);
  cvt(Wk, Wqkvb + (size_t)HD * HD,   kvdim * HD);
  cvt(Wv, Wqkvb + (size_t)(HD + kvdim) * HD, kvdim * HD);
  cvt(Wo, Wob,   (size_t)HD * HD);

  // fused QKV projection: [2048][6144]
  gemm_bt_kernel<bf16_t><<<dim3(NQKV / 128, S_LEN / 128), dim3(256), 0, stream>>>(
      Xb, Wqkvb, QKVb, S_LEN, NQKV, HD);

  // RoPE (scale 1/sqrt(128) folded into Q); K slice at col 4096
  rope_kernel<<<dim3(S_LEN * NH * 64 / 256), dim3(256), 0, stream>>>(
      QKVb, NH, NQKV, 0.08838834764831845f);
  rope_kernel<<<dim3(S_LEN * NKV * 64 / 256), dim3(256), 0, stream>>>(
      QKVb + HD, NKV, NQKV, 1.0f);

  // V^T ([1024][2048]) from V slice at col 5120
  transpose_kernel<<<dim3((int)kvdim / 64, S_LEN / 64), dim3(256), 0, stream>>>(
      QKVb + HD + kvdim, Vtb, S_LEN, (int)kvdim, NQKV);

  // attention
  attn_kernel<<<dim3(S_LEN / 64, NH), dim3(256), 0, stream>>>(QKVb, Vtb, AOb);

  // output projection (f32 out)
  gemm_bt_kernel<float><<<dim3(HD / 128, S_LEN / 128), dim3(256), 0, stream>>>(
      AOb, Wob, out, S_LEN, HD, HD);
}

// Round 4
// 403.644 us; speedup vs baseline: 1.6804x; 1.4697x over previous
//
#include <hip/hip_runtime.h>

// ---------------- problem constants ----------------
#define S_LEN 2048
#define HD    4096
#define NH    32
#define NKV   8
#define DH    128
#define NQKV  6144          // 4096 Q + 1024 K + 1024 V
#define QKV_STRIDE_B (NQKV * 2)

typedef __bf16 bf16_t;
typedef __bf16 bf16x8 __attribute__((ext_vector_type(8)));
typedef float  f32x4  __attribute__((ext_vector_type(4)));

// ---------------- helpers ----------------
__device__ inline unsigned short f2bf_bits(float f) {
  unsigned int u = __builtin_bit_cast(unsigned int, f);
  unsigned int r = (u + 0x7FFFu + ((u >> 16) & 1u)) >> 16;  // RNE
  return (unsigned short)r;
}
__device__ inline bf16_t f2bf(float f) {
  return __builtin_bit_cast(bf16_t, f2bf_bits(f));
}
__device__ inline float bf2f(bf16_t b) {
  unsigned int u = ((unsigned int)__builtin_bit_cast(unsigned short, b)) << 16;
  return __builtin_bit_cast(float, u);
}

__device__ inline void load_lds16(const void* g, void* l) {
  __builtin_amdgcn_global_load_lds(
      (__attribute__((address_space(1))) unsigned int*)(void*)g,
      (__attribute__((address_space(3))) unsigned int*)l, 16, 0, 0);
}

__device__ inline void store_out(float* p, float v)  { *p = v; }
__device__ inline void store_out(bf16_t* p, float v) { *p = f2bf(v); }

// ---------------- f32 -> bf16 convert (vectorized) ----------------
__global__ void cvt_kernel(const float* __restrict__ in, bf16_t* __restrict__ out, int n4) {
  int i = blockIdx.x * blockDim.x + threadIdx.x;
  if (i >= n4) return;
  float4 v = reinterpret_cast<const float4*>(in)[i];
  ushort4 o;
  o.x = f2bf_bits(v.x);
  o.y = f2bf_bits(v.y);
  o.z = f2bf_bits(v.z);
  o.w = f2bf_bits(v.w);
  reinterpret_cast<ushort4*>(out)[i] = o;
}

// ---------------- GEMM: C[M,N] = A[M,K] * B[N,K]^T  (m97 structure) ----------------
// 1-D grid with bijective XCD swizzle (m204); nbx = N/128.
template <typename OutT>
__global__ __launch_bounds__(256)
void gemm_bt_kernel(const bf16_t* __restrict__ A, const bf16_t* __restrict__ B,
                    OutT* __restrict__ C, int M, int N, int K, int nbx) {
  __shared__ __align__(16) bf16_t lA[128 * 32];
  __shared__ __align__(16) bf16_t lB[128 * 32];
  const int t = threadIdx.x;
  const int lane = t & 63, wave = t >> 6;

  // bijective XCD-aware remap
  const int nwg = gridDim.x;
  const int orig = blockIdx.x;
  const int xcd = orig & 7;
  const int qq = nwg >> 3, rr = nwg & 7;
  const int base = (xcd < rr) ? xcd * (qq + 1) : rr * (qq + 1) + (xcd - rr) * qq;
  const int wgid = base + (orig >> 3);
  const int row0 = (wgid / nbx) * 128, col0 = (wgid % nbx) * 128;

  const int wm = (wave >> 1) * 64, wn = (wave & 1) * 64;

  const int rA = wave * 32 + (lane >> 2);
  const int cA = (lane & 3) * 8;
  const char* Asrc0 = (const char*)(A + (size_t)(row0 + rA) * K + cA);
  const char* Asrc1 = (const char*)(A + (size_t)(row0 + rA + 16) * K + cA);
  const char* Bsrc0 = (const char*)(B + (size_t)(col0 + rA) * K + cA);
  const char* Bsrc1 = (const char*)(B + (size_t)(col0 + rA + 16) * K + cA);
  char* lAd = (char*)lA + wave * 2048;
  char* lBd = (char*)lB + wave * 2048;

  f32x4 acc[4][4] = {};
  const int fr = lane & 15, fq = lane >> 4;

  for (int k0 = 0; k0 < K; k0 += 32) {
    const size_t kb = (size_t)k0 * 2;
    load_lds16(Asrc0 + kb, lAd);
    load_lds16(Asrc1 + kb, lAd + 1024);
    load_lds16(Bsrc0 + kb, lBd);
    load_lds16(Bsrc1 + kb, lBd + 1024);
    __syncthreads();
    bf16x8 af[4], bfv[4];
#pragma unroll
    for (int mi = 0; mi < 4; mi++)
      af[mi] = *reinterpret_cast<const bf16x8*>(&lA[(wm + mi * 16 + fr) * 32 + fq * 8]);
#pragma unroll
    for (int ni = 0; ni < 4; ni++)
      bfv[ni] = *reinterpret_cast<const bf16x8*>(&lB[(wn + ni * 16 + fr) * 32 + fq * 8]);
#pragma unroll
    for (int mi = 0; mi < 4; mi++)
#pragma unroll
      for (int ni = 0; ni < 4; ni++)
        acc[mi][ni] = __builtin_amdgcn_mfma_f32_16x16x32_bf16(af[mi], bfv[ni], acc[mi][ni], 0, 0, 0);
    __syncthreads();
  }

#pragma unroll
  for (int mi = 0; mi < 4; mi++) {
#pragma unroll
    for (int r = 0; r < 4; r++) {
      int row = row0 + wm + mi * 16 + fq * 4 + r;
      OutT* Cp = C + (size_t)row * N + col0 + wn + fr;
#pragma unroll
      for (int ni = 0; ni < 4; ni++) store_out(Cp + ni * 16, acc[mi][ni][r]);
    }
  }
}

// ---------------- RoPE (in place, strided), folds score scale into Q ----------------
__global__ void rope_kernel(bf16_t* __restrict__ x, int heads, int rstride, float scale) {
  int idx = blockIdx.x * blockDim.x + threadIdx.x;  // total = S*heads*64
  int i = idx & 63;
  int h = (idx >> 6) % heads;
  int s = idx / (64 * heads);
  const float NEG_LOG1E4_64 = -0.14391156f;  // -ln(10000)/64
  float freq = __expf((float)i * NEG_LOG1E4_64);
  float ang = (float)s * freq;
  float sn, cs;
  __sincosf(ang, &sn, &cs);
  bf16_t* p = x + (size_t)s * rstride + h * DH;
  float x1 = bf2f(p[i]);
  float x2 = bf2f(p[i + 64]);
  p[i]      = f2bf((x1 * cs - x2 * sn) * scale);
  p[i + 64] = f2bf((x2 * cs + x1 * sn) * scale);
}

// ---------------- transpose [R][C] -> [C][R] (bf16), strided input ----------------
__global__ void transpose_kernel(const bf16_t* __restrict__ in, bf16_t* __restrict__ out,
                                 int R, int C, int in_rstride) {
  __shared__ bf16_t tile[64][65];
  int c0 = blockIdx.x * 64, r0 = blockIdx.y * 64;
  int t = threadIdx.x;
#pragma unroll
  for (int i = 0; i < 16; i++) {
    int idx = t + i * 256;
    int r = idx >> 6, c = idx & 63;
    tile[r][c] = in[(size_t)(r0 + r) * in_rstride + c0 + c];
  }
  __syncthreads();
#pragma unroll
  for (int i = 0; i < 16; i++) {
    int idx = t + i * 256;
    int r = idx >> 6, c = idx & 63;
    out[(size_t)(c0 + r) * R + r0 + c] = tile[c][r];
  }
}

// ---------------- flash attention (causal, GQA) ----------------
// grid (16, NH): workgroup p handles Q-blocks {31-p, p} -> exactly 33 KV-tiles
// each (perfect balance; 512 blocks = 2/CU, all resident). 256 threads = 4 waves.
// KVBLK=64, K+V double-buffered LDS, one barrier/tile; XOR-swizzle slot^=(row&15)
// via pre-swizzled global source. P roundtrip via lP[16][72].
__global__ __launch_bounds__(256)
void attn_kernel(const bf16_t* __restrict__ Qkv, const bf16_t* __restrict__ Vt,
                 bf16_t* __restrict__ O) {
  __shared__ __align__(16) char lK[2][64 * 256];   // 16 KB x2
  __shared__ __align__(16) char lV[2][64 * 256];   // 16 KB x2
  __shared__ __align__(16) bf16_t lP[4][16 * 72];  // 9216 B

  const int t = threadIdx.x, lane = t & 63, wave = t >> 6;
  const int h = blockIdx.y, kvh = h >> 2;
  const int pid = blockIdx.x;                      // 0..15
  const int fr = lane & 15, fq = lane >> 4;

  // ---- staging constants (per-thread) ----
  const int gc = wave * 4 + (lane >> 4);
  const int sS = (lane & 15) ^ (gc & 15);
  const char* KsrcB = (const char*)(Qkv + HD + (size_t)kvh * DH) +
                      (size_t)gc * QKV_STRIDE_B + sS * 16;
  const int dVc = gc * 2 + (sS >> 3);
  const char* VsrcB = (const char*)Vt + (size_t)kvh * DH * S_LEN * 2 +
                      (size_t)dVc * 4096 + (sS & 7) * 16;
  char* dKw = (char*)lK[0] + wave * 1024;
  char* dVw = (char*)lV[0] + wave * 1024;

  auto stage = [&](int buf, int kv0) {
    char* dk = dKw + buf * (64 * 256);
    char* dv = dVw + buf * (64 * 256);
    const char* ks = KsrcB + (size_t)kv0 * QKV_STRIDE_B;
    const char* vs = VsrcB + (size_t)kv0 * 2;
#pragma unroll
    for (int i = 0; i < 4; i++) {
      load_lds16(ks + i * (16 * QKV_STRIDE_B), dk + i * 4096);
      load_lds16(vs + i * (size_t)(32 * 4096), dv + i * 4096);
    }
  };

  stage(0, 0);
  int buf = 0;

  for (int pass = 0; pass < 2; pass++) {
    const int qb = pass ? pid : (31 - pid);        // long block first
    const int q0 = qb * 64 + wave * 16;

    // Q fragments for this pass
    bf16x8 qf[4];
    const bf16_t* Qp = Qkv + (size_t)(q0 + fr) * NQKV + h * DH + fq * 8;
#pragma unroll
    for (int kt = 0; kt < 4; kt++)
      qf[kt] = *reinterpret_cast<const bf16x8*>(Qp + kt * 32);

    f32x4 o_acc[8] = {};
    float m_run[4] = {-1e30f, -1e30f, -1e30f, -1e30f};
    float l_run[4] = {0.f, 0.f, 0.f, 0.f};

    for (int tt = 0; tt <= qb; tt++) {
      __syncthreads();  // implicit vmcnt(0): prefetch landed; prev compute done
      if (tt < qb)            stage(buf ^ 1, (tt + 1) * 64);
      else if (pass == 0)     stage(buf ^ 1, 0);   // pass-B tile 0

      const char* cK = lK[buf];
      const char* cV = lV[buf];
      const bool diag = (tt == qb);

      // ---- S = Q K^T : 16 MFMA ----
      f32x4 s_acc[4] = {};
      __builtin_amdgcn_s_setprio(1);
#pragma unroll
      for (int nt = 0; nt < 4; nt++) {
        const char* rowp = cK + (nt * 16 + fr) * 256;
#pragma unroll
        for (int kt = 0; kt < 4; kt++) {
          const bf16x8 kf = *reinterpret_cast<const bf16x8*>(
              rowp + (((kt * 4 + fq) ^ fr) << 4));
          s_acc[nt] = __builtin_amdgcn_mfma_f32_16x16x32_bf16(qf[kt], kf, s_acc[nt], 0, 0, 0);
        }
      }
      __builtin_amdgcn_s_setprio(0);

      // ---- online softmax, defer-max (THR=8) ----
      float pmax[4];
#pragma unroll
      for (int r = 0; r < 4; r++) {
        if (diag) {
          const int qrel = wave * 16 + fq * 4 + r;
#pragma unroll
          for (int nt = 0; nt < 4; nt++)
            if (nt * 16 + fr > qrel) s_acc[nt][r] = -1e30f;
        }
        float mr = fmaxf(fmaxf(s_acc[0][r], s_acc[1][r]), fmaxf(s_acc[2][r], s_acc[3][r]));
#pragma unroll
        for (int off = 1; off < 16; off <<= 1) mr = fmaxf(mr, __shfl_xor(mr, off, 16));
        pmax[r] = mr;
      }
      bool nb = (pmax[0] > m_run[0] + 8.f) || (pmax[1] > m_run[1] + 8.f) ||
                (pmax[2] > m_run[2] + 8.f) || (pmax[3] > m_run[3] + 8.f);
      if (__any(nb)) {
#pragma unroll
        for (int r = 0; r < 4; r++) {
          float mnew = fmaxf(m_run[r], pmax[r]);
          float alpha = __expf(m_run[r] - mnew);
#pragma unroll
          for (int ni = 0; ni < 8; ni++) o_acc[ni][r] *= alpha;
          l_run[r] *= alpha;
          m_run[r] = mnew;
        }
      }
      bf16_t* lPw = lP[wave];
#pragma unroll
      for (int r = 0; r < 4; r++) {
        float p0 = __expf(s_acc[0][r] - m_run[r]);
        float p1 = __expf(s_acc[1][r] - m_run[r]);
        float p2 = __expf(s_acc[2][r] - m_run[r]);
        float p3 = __expf(s_acc[3][r] - m_run[r]);
        float sr = (p0 + p1) + (p2 + p3);
#pragma unroll
        for (int off = 1; off < 16; off <<= 1) sr += __shfl_xor(sr, off, 16);
        l_run[r] += sr;
        const int row = fq * 4 + r;
        lPw[row * 72 + fr]      = f2bf(p0);
        lPw[row * 72 + 16 + fr] = f2bf(p1);
        lPw[row * 72 + 32 + fr] = f2bf(p2);
        lPw[row * 72 + 48 + fr] = f2bf(p3);
      }

      // ---- O += P V : 16 MFMA ----
#pragma unroll
      for (int kk = 0; kk < 2; kk++) {
        const bf16x8 pf = *reinterpret_cast<const bf16x8*>(lPw + fr * 72 + kk * 32 + fq * 8);
        __builtin_amdgcn_s_setprio(1);
#pragma unroll
        for (int ni = 0; ni < 8; ni++) {
          const int d = ni * 16 + fr;
          const int g = d >> 1;
          const int slot = ((d & 1) * 8 + kk * 4 + fq) ^ (g & 15);
          const bf16x8 vf = *reinterpret_cast<const bf16x8*>(cV + g * 256 + (slot << 4));
          o_acc[ni] = __builtin_amdgcn_mfma_f32_16x16x32_bf16(pf, vf, o_acc[ni], 0, 0, 0);
        }
        __builtin_amdgcn_s_setprio(0);
      }
      buf ^= 1;
    }

    // ---- epilogue: normalize and store this pass's rows ----
#pragma unroll
    for (int r = 0; r < 4; r++) {
      int qrow = q0 + fq * 4 + r;
      float inv = 1.0f / l_run[r];
      bf16_t* Op = O + ((size_t)qrow * NH + h) * DH + fr;
#pragma unroll
      for (int ni = 0; ni < 8; ni++) Op[ni * 16] = f2bf(o_acc[ni][r] * inv);
    }
  }
}

// ---------------- launch ----------------
extern "C" void kernel_launch(void* const* d_in, const int* in_sizes, int n_in,
                              void* d_out, int out_size, void* d_ws, size_t ws_size,
                              hipStream_t stream) {
  const float* X  = (const float*)d_in[0];
  const float* Wq = (const float*)d_in[1];
  const float* Wk = (const float*)d_in[2];
  const float* Wv = (const float*)d_in[3];
  const float* Wo = (const float*)d_in[4];
  float* out = (float*)d_out;

  char* ws = (char*)d_ws;
  size_t off = 0;
  auto alloc = [&](size_t bytes) {
    char* p = ws + off;
    off += (bytes + 255) & ~(size_t)255;
    return p;
  };
  const size_t kvdim = (size_t)NKV * DH;           // 1024
  bf16_t* Xb    = (bf16_t*)alloc((size_t)S_LEN * HD * 2);
  bf16_t* Wqkvb = (bf16_t*)alloc((size_t)NQKV * HD * 2);   // [6144][4096]
  bf16_t* Wob   = (bf16_t*)alloc((size_t)HD * HD * 2);
  bf16_t* QKVb  = (bf16_t*)alloc((size_t)S_LEN * NQKV * 2);  // [2048][6144]
  bf16_t* Vtb   = (bf16_t*)alloc((size_t)S_LEN * kvdim * 2); // [1024][2048]
  bf16_t* AOb   = (bf16_t*)alloc((size_t)S_LEN * HD * 2);
  (void)ws_size;

  auto cvt = [&](const float* in, bf16_t* o, size_t n) {
    int n4 = (int)(n / 4);
    cvt_kernel<<<dim3((n4 + 255) / 256), dim3(256), 0, stream>>>(in, o, n4);
  };
  cvt(X,  Xb,    (size_t)S_LEN * HD);
  cvt(Wq, Wqkvb, (size_t)HD * HD);
  cvt(Wk, Wqkvb + (size_t)HD * HD,   kvdim * HD);
  cvt(Wv, Wqkvb + (size_t)(HD + kvdim) * HD, kvdim * HD);
  cvt(Wo, Wob,   (size_t)HD * HD);

  // fused QKV projection: [2048][6144]
  {
    int nbx = NQKV / 128, nby = S_LEN / 128;
    gemm_bt_kernel<bf16_t><<<dim3(nbx * nby), dim3(256), 0, stream>>>(
        Xb, Wqkvb, QKVb, S_LEN, NQKV, HD, nbx);
  }

  // RoPE (scale 1/sqrt(128) folded into Q); K slice at col 4096
  rope_kernel<<<dim3(S_LEN * NH * 64 / 256), dim3(256), 0, stream>>>(
      QKVb, NH, NQKV, 0.08838834764831845f);
  rope_kernel<<<dim3(S_LEN * NKV * 64 / 256), dim3(256), 0, stream>>>(
      QKVb + HD, NKV, NQKV, 1.0f);

  // V^T ([1024][2048]) from V slice at col 5120
  transpose_kernel<<<dim3((int)kvdim / 64, S_LEN / 64), dim3(256), 0, stream>>>(
      QKVb + HD + kvdim, Vtb, S_LEN, (int)kvdim, NQKV);

  // attention (paired causal blocks: perfect balance)
  attn_kernel<<<dim3(16, NH), dim3(256), 0, stream>>>(QKVb, Vtb, AOb);

  // output projection (f32 out)
  {
    int nbx = HD / 128, nby = S_LEN / 128;
    gemm_bt_kernel<float><<<dim3(nbx * nby), dim3(256), 0, stream>>>(
        AOb, Wob, out, S_LEN, HD, HD, nbx);
  }
}

// Round 8
// 401.097 us; speedup vs baseline: 1.6911x; 1.0064x over previous
//
#include <hip/hip_runtime.h>

// ---------------- problem constants ----------------
#define S_LEN 2048
#define HD    4096
#define NH    32
#define NKV   8
#define DH    128
#define NQKV  6144          // 4096 Q + 1024 K + 1024 V
#define QKV_STRIDE_B (NQKV * 2)

typedef __bf16 bf16_t;
typedef __bf16 bf16x8 __attribute__((ext_vector_type(8)));
typedef float  f32x4  __attribute__((ext_vector_type(4)));
typedef unsigned short ushort8v __attribute__((ext_vector_type(8)));

// ---------------- helpers ----------------
__device__ inline unsigned short f2bf_bits(float f) {
  unsigned int u = __builtin_bit_cast(unsigned int, f);
  unsigned int r = (u + 0x7FFFu + ((u >> 16) & 1u)) >> 16;  // RNE
  return (unsigned short)r;
}
__device__ inline bf16_t f2bf(float f) {
  return __builtin_bit_cast(bf16_t, f2bf_bits(f));
}
__device__ inline float bf2f(bf16_t b) {
  unsigned int u = ((unsigned int)__builtin_bit_cast(unsigned short, b)) << 16;
  return __builtin_bit_cast(float, u);
}

__device__ inline void load_lds16(const void* g, void* l) {
  __builtin_amdgcn_global_load_lds(
      (__attribute__((address_space(1))) unsigned int*)(void*)g,
      (__attribute__((address_space(3))) unsigned int*)l, 16, 0, 0);
}

__device__ inline void store_out(float* p, float v)  { *p = v; }
__device__ inline void store_out(bf16_t* p, float v) { *p = f2bf(v); }

// ---------------- f32 -> bf16 convert (grid-stride, 8 elems/thread) ----------------
__global__ void cvt_kernel(const float* __restrict__ in, bf16_t* __restrict__ out, int n8) {
  int stride = gridDim.x * blockDim.x;
  for (int i = blockIdx.x * blockDim.x + threadIdx.x; i < n8; i += stride) {
    float4 v0 = reinterpret_cast<const float4*>(in)[i * 2];
    float4 v1 = reinterpret_cast<const float4*>(in)[i * 2 + 1];
    ushort8v o;
    o[0] = f2bf_bits(v0.x); o[1] = f2bf_bits(v0.y);
    o[2] = f2bf_bits(v0.z); o[3] = f2bf_bits(v0.w);
    o[4] = f2bf_bits(v1.x); o[5] = f2bf_bits(v1.y);
    o[6] = f2bf_bits(v1.z); o[7] = f2bf_bits(v1.w);
    reinterpret_cast<ushort8v*>(out)[i] = o;
  }
}

// ---------------- GEMM: C[M,N] = A[M,K] * B[N,K]^T  (m97 structure, verbatim R4) ----
// 1-D grid with bijective XCD swizzle (m204); nbx = N/128.
template <typename OutT>
__global__ __launch_bounds__(256)
void gemm_bt_kernel(const bf16_t* __restrict__ A, const bf16_t* __restrict__ B,
                    OutT* __restrict__ C, int M, int N, int K, int nbx) {
  __shared__ __align__(16) bf16_t lA[128 * 32];
  __shared__ __align__(16) bf16_t lB[128 * 32];
  const int t = threadIdx.x;
  const int lane = t & 63, wave = t >> 6;

  // bijective XCD-aware remap
  const int nwg = gridDim.x;
  const int orig = blockIdx.x;
  const int xcd = orig & 7;
  const int qq = nwg >> 3, rr = nwg & 7;
  const int base = (xcd < rr) ? xcd * (qq + 1) : rr * (qq + 1) + (xcd - rr) * qq;
  const int wgid = base + (orig >> 3);
  const int row0 = (wgid / nbx) * 128, col0 = (wgid % nbx) * 128;

  const int wm = (wave >> 1) * 64, wn = (wave & 1) * 64;

  const int rA = wave * 32 + (lane >> 2);
  const int cA = (lane & 3) * 8;
  const char* Asrc0 = (const char*)(A + (size_t)(row0 + rA) * K + cA);
  const char* Asrc1 = (const char*)(A + (size_t)(row0 + rA + 16) * K + cA);
  const char* Bsrc0 = (const char*)(B + (size_t)(col0 + rA) * K + cA);
  const char* Bsrc1 = (const char*)(B + (size_t)(col0 + rA + 16) * K + cA);
  char* lAd = (char*)lA + wave * 2048;
  char* lBd = (char*)lB + wave * 2048;

  f32x4 acc[4][4] = {};
  const int fr = lane & 15, fq = lane >> 4;

  for (int k0 = 0; k0 < K; k0 += 32) {
    const size_t kb = (size_t)k0 * 2;
    load_lds16(Asrc0 + kb, lAd);
    load_lds16(Asrc1 + kb, lAd + 1024);
    load_lds16(Bsrc0 + kb, lBd);
    load_lds16(Bsrc1 + kb, lBd + 1024);
    __syncthreads();
    bf16x8 af[4], bfv[4];
#pragma unroll
    for (int mi = 0; mi < 4; mi++)
      af[mi] = *reinterpret_cast<const bf16x8*>(&lA[(wm + mi * 16 + fr) * 32 + fq * 8]);
#pragma unroll
    for (int ni = 0; ni < 4; ni++)
      bfv[ni] = *reinterpret_cast<const bf16x8*>(&lB[(wn + ni * 16 + fr) * 32 + fq * 8]);
#pragma unroll
    for (int mi = 0; mi < 4; mi++)
#pragma unroll
      for (int ni = 0; ni < 4; ni++)
        acc[mi][ni] = __builtin_amdgcn_mfma_f32_16x16x32_bf16(af[mi], bfv[ni], acc[mi][ni], 0, 0, 0);
    __syncthreads();
  }

#pragma unroll
  for (int mi = 0; mi < 4; mi++) {
#pragma unroll
    for (int r = 0; r < 4; r++) {
      int row = row0 + wm + mi * 16 + fq * 4 + r;
      OutT* Cp = C + (size_t)row * N + col0 + wn + fr;
#pragma unroll
      for (int ni = 0; ni < 4; ni++) store_out(Cp + ni * 16, acc[mi][ni][r]);
    }
  }
}

// ---------------- RoPE (in place, strided), folds score scale into Q ----------------
__global__ void rope_kernel(bf16_t* __restrict__ x, int heads, int rstride, float scale) {
  int idx = blockIdx.x * blockDim.x + threadIdx.x;  // total = S*heads*64
  int i = idx & 63;
  int h = (idx >> 6) % heads;
  int s = idx / (64 * heads);
  const float NEG_LOG1E4_64 = -0.14391156f;  // -ln(10000)/64
  float freq = __expf((float)i * NEG_LOG1E4_64);
  float ang = (float)s * freq;
  float sn, cs;
  __sincosf(ang, &sn, &cs);
  bf16_t* p = x + (size_t)s * rstride + h * DH;
  float x1 = bf2f(p[i]);
  float x2 = bf2f(p[i + 64]);
  p[i]      = f2bf((x1 * cs - x2 * sn) * scale);
  p[i + 64] = f2bf((x2 * cs + x1 * sn) * scale);
}

// ---------------- transpose [R][C] -> [C][R] (bf16), strided input ----------------
__global__ void transpose_kernel(const bf16_t* __restrict__ in, bf16_t* __restrict__ out,
                                 int R, int C, int in_rstride) {
  __shared__ bf16_t tile[64][65];
  int c0 = blockIdx.x * 64, r0 = blockIdx.y * 64;
  int t = threadIdx.x;
#pragma unroll
  for (int i = 0; i < 16; i++) {
    int idx = t + i * 256;
    int r = idx >> 6, c = idx & 63;
    tile[r][c] = in[(size_t)(r0 + r) * in_rstride + c0 + c];
  }
  __syncthreads();
#pragma unroll
  for (int i = 0; i < 16; i++) {
    int idx = t + i * 256;
    int r = idx >> 6, c = idx & 63;
    out[(size_t)(c0 + r) * R + r0 + c] = tile[c][r];
  }
}

// ---------------- flash attention (causal, GQA) ----------------
// grid (16, NH): workgroup p handles Q-blocks {31-p, p} -> exactly 33 KV-tiles
// each (perfect balance; 512 blocks = 2/CU, all resident). 256 threads = 4 waves.
// KVBLK=64, K+V double-buffered LDS, one barrier/tile; XOR-swizzle slot^=(row&15)
// via pre-swizzled global source. P roundtrip via lP[16][72].
__global__ __launch_bounds__(256)
void attn_kernel(const bf16_t* __restrict__ Qkv, const bf16_t* __restrict__ Vt,
                 bf16_t* __restrict__ O) {
  __shared__ __align__(16) char lK[2][64 * 256];   // 16 KB x2
  __shared__ __align__(16) char lV[2][64 * 256];   // 16 KB x2
  __shared__ __align__(16) bf16_t lP[4][16 * 72];  // 9216 B

  const int t = threadIdx.x, lane = t & 63, wave = t >> 6;
  const int h = blockIdx.y, kvh = h >> 2;
  const int pid = blockIdx.x;                      // 0..15
  const int fr = lane & 15, fq = lane >> 4;

  // ---- staging constants (per-thread) ----
  const int gc = wave * 4 + (lane >> 4);
  const int sS = (lane & 15) ^ (gc & 15);
  const char* KsrcB = (const char*)(Qkv + HD + (size_t)kvh * DH) +
                      (size_t)gc * QKV_STRIDE_B + sS * 16;
  const int dVc = gc * 2 + (sS >> 3);
  const char* VsrcB = (const char*)Vt + (size_t)kvh * DH * S_LEN * 2 +
                      (size_t)dVc * 4096 + (sS & 7) * 16;
  char* dKw = (char*)lK[0] + wave * 1024;
  char* dVw = (char*)lV[0] + wave * 1024;

  auto stage = [&](int buf, int kv0) {
    char* dk = dKw + buf * (64 * 256);
    char* dv = dVw + buf * (64 * 256);
    const char* ks = KsrcB + (size_t)kv0 * QKV_STRIDE_B;
    const char* vs = VsrcB + (size_t)kv0 * 2;
#pragma unroll
    for (int i = 0; i < 4; i++) {
      load_lds16(ks + i * (16 * QKV_STRIDE_B), dk + i * 4096);
      load_lds16(vs + i * (size_t)(32 * 4096), dv + i * 4096);
    }
  };

  stage(0, 0);
  int buf = 0;

  for (int pass = 0; pass < 2; pass++) {
    const int qb = pass ? pid : (31 - pid);        // long block first
    const int q0 = qb * 64 + wave * 16;

    // Q fragments for this pass
    bf16x8 qf[4];
    const bf16_t* Qp = Qkv + (size_t)(q0 + fr) * NQKV + h * DH + fq * 8;
#pragma unroll
    for (int kt = 0; kt < 4; kt++)
      qf[kt] = *reinterpret_cast<const bf16x8*>(Qp + kt * 32);

    f32x4 o_acc[8] = {};
    float m_run[4] = {-1e30f, -1e30f, -1e30f, -1e30f};
    float l_run[4] = {0.f, 0.f, 0.f, 0.f};

    for (int tt = 0; tt <= qb; tt++) {
      __syncthreads();  // implicit vmcnt(0): prefetch landed; prev compute done
      if (tt < qb)            stage(buf ^ 1, (tt + 1) * 64);
      else if (pass == 0)     stage(buf ^ 1, 0);   // pass-B tile 0

      const char* cK = lK[buf];
      const char* cV = lV[buf];
      const bool diag = (tt == qb);

      // ---- S = Q K^T : 16 MFMA ----
      f32x4 s_acc[4] = {};
      __builtin_amdgcn_s_setprio(1);
#pragma unroll
      for (int nt = 0; nt < 4; nt++) {
        const char* rowp = cK + (nt * 16 + fr) * 256;
#pragma unroll
        for (int kt = 0; kt < 4; kt++) {
          const bf16x8 kf = *reinterpret_cast<const bf16x8*>(
              rowp + (((kt * 4 + fq) ^ fr) << 4));
          s_acc[nt] = __builtin_amdgcn_mfma_f32_16x16x32_bf16(qf[kt], kf, s_acc[nt], 0, 0, 0);
        }
      }
      __builtin_amdgcn_s_setprio(0);

      // ---- online softmax, defer-max (THR=8) ----
      float pmax[4];
#pragma unroll
      for (int r = 0; r < 4; r++) {
        if (diag) {
          const int qrel = wave * 16 + fq * 4 + r;
#pragma unroll
          for (int nt = 0; nt < 4; nt++)
            if (nt * 16 + fr > qrel) s_acc[nt][r] = -1e30f;
        }
        float mr = fmaxf(fmaxf(s_acc[0][r], s_acc[1][r]), fmaxf(s_acc[2][r], s_acc[3][r]));
#pragma unroll
        for (int off = 1; off < 16; off <<= 1) mr = fmaxf(mr, __shfl_xor(mr, off, 16));
        pmax[r] = mr;
      }
      bool nb = (pmax[0] > m_run[0] + 8.f) || (pmax[1] > m_run[1] + 8.f) ||
                (pmax[2] > m_run[2] + 8.f) || (pmax[3] > m_run[3] + 8.f);
      if (__any(nb)) {
#pragma unroll
        for (int r = 0; r < 4; r++) {
          float mnew = fmaxf(m_run[r], pmax[r]);
          float alpha = __expf(m_run[r] - mnew);
#pragma unroll
          for (int ni = 0; ni < 8; ni++) o_acc[ni][r] *= alpha;
          l_run[r] *= alpha;
          m_run[r] = mnew;
        }
      }
      bf16_t* lPw = lP[wave];
#pragma unroll
      for (int r = 0; r < 4; r++) {
        float p0 = __expf(s_acc[0][r] - m_run[r]);
        float p1 = __expf(s_acc[1][r] - m_run[r]);
        float p2 = __expf(s_acc[2][r] - m_run[r]);
        float p3 = __expf(s_acc[3][r] - m_run[r]);
        float sr = (p0 + p1) + (p2 + p3);
#pragma unroll
        for (int off = 1; off < 16; off <<= 1) sr += __shfl_xor(sr, off, 16);
        l_run[r] += sr;
        const int row = fq * 4 + r;
        lPw[row * 72 + fr]      = f2bf(p0);
        lPw[row * 72 + 16 + fr] = f2bf(p1);
        lPw[row * 72 + 32 + fr] = f2bf(p2);
        lPw[row * 72 + 48 + fr] = f2bf(p3);
      }

      // ---- O += P V : 16 MFMA ----
#pragma unroll
      for (int kk = 0; kk < 2; kk++) {
        const bf16x8 pf = *reinterpret_cast<const bf16x8*>(lPw + fr * 72 + kk * 32 + fq * 8);
        __builtin_amdgcn_s_setprio(1);
#pragma unroll
        for (int ni = 0; ni < 8; ni++) {
          const int d = ni * 16 + fr;
          const int g = d >> 1;
          const int slot = ((d & 1) * 8 + kk * 4 + fq) ^ (g & 15);
          const bf16x8 vf = *reinterpret_cast<const bf16x8*>(cV + g * 256 + (slot << 4));
          o_acc[ni] = __builtin_amdgcn_mfma_f32_16x16x32_bf16(pf, vf, o_acc[ni], 0, 0, 0);
        }
        __builtin_amdgcn_s_setprio(0);
      }
      buf ^= 1;
    }

    // ---- epilogue: normalize and store this pass's rows ----
#pragma unroll
    for (int r = 0; r < 4; r++) {
      int qrow = q0 + fq * 4 + r;
      float inv = 1.0f / l_run[r];
      bf16_t* Op = O + ((size_t)qrow * NH + h) * DH + fr;
#pragma unroll
      for (int ni = 0; ni < 8; ni++) Op[ni * 16] = f2bf(o_acc[ni][r] * inv);
    }
  }
}

// ---------------- launch ----------------
extern "C" void kernel_launch(void* const* d_in, const int* in_sizes, int n_in,
                              void* d_out, int out_size, void* d_ws, size_t ws_size,
                              hipStream_t stream) {
  const float* X  = (const float*)d_in[0];
  const float* Wq = (const float*)d_in[1];
  const float* Wk = (const float*)d_in[2];
  const float* Wv = (const float*)d_in[3];
  const float* Wo = (const float*)d_in[4];
  float* out = (float*)d_out;

  char* ws = (char*)d_ws;
  size_t off = 0;
  auto alloc = [&](size_t bytes) {
    char* p = ws + off;
    off += (bytes + 255) & ~(size_t)255;
    return p;
  };
  const size_t kvdim = (size_t)NKV * DH;           // 1024
  bf16_t* Xb    = (bf16_t*)alloc((size_t)S_LEN * HD * 2);
  bf16_t* Wqkvb = (bf16_t*)alloc((size_t)NQKV * HD * 2);   // [6144][4096]
  bf16_t* Wob   = (bf16_t*)alloc((size_t)HD * HD * 2);
  bf16_t* QKVb  = (bf16_t*)alloc((size_t)S_LEN * NQKV * 2);  // [2048][6144]
  bf16_t* Vtb   = (bf16_t*)alloc((size_t)S_LEN * kvdim * 2); // [1024][2048]
  bf16_t* AOb   = (bf16_t*)alloc((size_t)S_LEN * HD * 2);
  (void)ws_size;

  auto cvt = [&](const float* in, bf16_t* o, size_t n) {
    int n8 = (int)(n / 8);
    int blocks = (n8 + 255) / 256;
    if (blocks > 2048) blocks = 2048;
    cvt_kernel<<<dim3(blocks), dim3(256), 0, stream>>>(in, o, n8);
  };
  cvt(X,  Xb,    (size_t)S_LEN * HD);
  cvt(Wq, Wqkvb, (size_t)HD * HD);
  cvt(Wk, Wqkvb + (size_t)HD * HD,   kvdim * HD);
  cvt(Wv, Wqkvb + (size_t)(HD + kvdim) * HD, kvdim * HD);
  cvt(Wo, Wob,   (size_t)HD * HD);

  // fused QKV projection: [2048][6144]
  {
    int nbx = NQKV / 128, nby = S_LEN / 128;
    gemm_bt_kernel<bf16_t><<<dim3(nbx * nby), dim3(256), 0, stream>>>(
        Xb, Wqkvb, QKVb, S_LEN, NQKV, HD, nbx);
  }

  // RoPE (scale 1/sqrt(128) folded into Q); K slice at col 4096
  rope_kernel<<<dim3(S_LEN * NH * 64 / 256), dim3(256), 0, stream>>>(
      QKVb, NH, NQKV, 0.08838834764831845f);
  rope_kernel<<<dim3(S_LEN * NKV * 64 / 256), dim3(256), 0, stream>>>(
      QKVb + HD, NKV, NQKV, 1.0f);

  // V^T ([1024][2048]) from V slice at col 5120
  transpose_kernel<<<dim3((int)kvdim / 64, S_LEN / 64), dim3(256), 0, stream>>>(
      QKVb + HD + kvdim, Vtb, S_LEN, (int)kvdim, NQKV);

  // attention (paired causal blocks: perfect balance)
  attn_kernel<<<dim3(16, NH), dim3(256), 0, stream>>>(QKVb, Vtb, AOb);

  // output projection (f32 out)
  {
    int nbx = HD / 128, nby = S_LEN / 128;
    gemm_bt_kernel<float><<<dim3(nbx * nby), dim3(256), 0, stream>>>(
        AOb, Wob, out, S_LEN, HD, HD, nbx);
  }
}

// Round 11
// 371.510 us; speedup vs baseline: 1.8258x; 1.0796x over previous
//
#include <hip/hip_runtime.h>

// ---------------- problem constants ----------------
#define S_LEN 2048
#define HD    4096
#define NH    32
#define NKV   8
#define DH    128
#define NQKV  6144          // 4096 Q + 1024 K + 1024 V
#define QKV_STRIDE_B (NQKV * 2)

typedef __bf16 bf16_t;
typedef __bf16 bf16x8 __attribute__((ext_vector_type(8)));
typedef float  f32x4  __attribute__((ext_vector_type(4)));
typedef unsigned short ushort8v __attribute__((ext_vector_type(8)));

// ---------------- helpers ----------------
__device__ inline unsigned short f2bf_bits(float f) {
  unsigned int u = __builtin_bit_cast(unsigned int, f);
  unsigned int r = (u + 0x7FFFu + ((u >> 16) & 1u)) >> 16;  // RNE
  return (unsigned short)r;
}
__device__ inline bf16_t f2bf(float f) {
  return __builtin_bit_cast(bf16_t, f2bf_bits(f));
}
__device__ inline float bf2f(bf16_t b) {
  unsigned int u = ((unsigned int)__builtin_bit_cast(unsigned short, b)) << 16;
  return __builtin_bit_cast(float, u);
}

__device__ inline void load_lds16(const void* g, void* l) {
  __builtin_amdgcn_global_load_lds(
      (__attribute__((address_space(1))) unsigned int*)(void*)g,
      (__attribute__((address_space(3))) unsigned int*)l, 16, 0, 0);
}

__device__ inline void store_out(float* p, float v)  { *p = v; }
__device__ inline void store_out(bf16_t* p, float v) { *p = f2bf(v); }

#define SCHED0 __builtin_amdgcn_sched_barrier(0)

// ---------------- f32 -> bf16 convert (grid-stride, 8 elems/thread) ----------------
__global__ void cvt_kernel(const float* __restrict__ in, bf16_t* __restrict__ out, int n8) {
  int stride = gridDim.x * blockDim.x;
  for (int i = blockIdx.x * blockDim.x + threadIdx.x; i < n8; i += stride) {
    float4 v0 = reinterpret_cast<const float4*>(in)[i * 2];
    float4 v1 = reinterpret_cast<const float4*>(in)[i * 2 + 1];
    ushort8v o;
    o[0] = f2bf_bits(v0.x); o[1] = f2bf_bits(v0.y);
    o[2] = f2bf_bits(v0.z); o[3] = f2bf_bits(v0.w);
    o[4] = f2bf_bits(v1.x); o[5] = f2bf_bits(v1.y);
    o[6] = f2bf_bits(v1.z); o[7] = f2bf_bits(v1.w);
    reinterpret_cast<ushort8v*>(out)[i] = o;
  }
}

// ---------------- GEMM: C[M,N] = A[M,K] * B[N,K]^T ----------------
// BK=64 realized as TWO verbatim copies of the R8-verified BK=32 structure:
// four single-buffered 8 KB LDS tiles (lA/lB = K-half 0, lA2/lB2 = K-half 1),
// R8's exact dest arithmetic (wave*2048, +1024 chunks) and source arithmetic
// (rA = wave*32 + lane>>2, cA = (lane&3)*8; half-1 sources at +64 bytes).
// One sync pair per 64-wide K-step -> half the barrier drains of R8, 32 MFMA
// per interval. sched_barrier(0) brackets both __syncthreads to pin the DMA
// intrinsics against compiler motion across the barriers (R10 failure class).
template <typename OutT>
__global__ __launch_bounds__(256)
void gemm_bt32x2_kernel(const bf16_t* __restrict__ A, const bf16_t* __restrict__ B,
                        OutT* __restrict__ C, int M, int N, int K, int nbx) {
  __shared__ __align__(16) bf16_t lA [128 * 32];
  __shared__ __align__(16) bf16_t lB [128 * 32];
  __shared__ __align__(16) bf16_t lA2[128 * 32];
  __shared__ __align__(16) bf16_t lB2[128 * 32];
  const int t = threadIdx.x;
  const int lane = t & 63, wave = t >> 6;

  // bijective XCD-aware remap (verbatim R8)
  const int nwg = gridDim.x;
  const int orig = blockIdx.x;
  const int xcd = orig & 7;
  const int qq = nwg >> 3, rr = nwg & 7;
  const int base = (xcd < rr) ? xcd * (qq + 1) : rr * (qq + 1) + (xcd - rr) * qq;
  const int wgid = base + (orig >> 3);
  const int row0 = (wgid / nbx) * 128, col0 = (wgid % nbx) * 128;

  const int wm = (wave >> 1) * 64, wn = (wave & 1) * 64;

  // staging geometry (verbatim R8)
  const int rA = wave * 32 + (lane >> 2);
  const int cA = (lane & 3) * 8;
  const char* Asrc0 = (const char*)(A + (size_t)(row0 + rA) * K + cA);
  const char* Asrc1 = (const char*)(A + (size_t)(row0 + rA + 16) * K + cA);
  const char* Bsrc0 = (const char*)(B + (size_t)(col0 + rA) * K + cA);
  const char* Bsrc1 = (const char*)(B + (size_t)(col0 + rA + 16) * K + cA);
  char* lAd  = (char*)lA  + wave * 2048;
  char* lBd  = (char*)lB  + wave * 2048;
  char* lA2d = (char*)lA2 + wave * 2048;
  char* lB2d = (char*)lB2 + wave * 2048;

  f32x4 acc[4][4] = {};
  const int fr = lane & 15, fq = lane >> 4;

  for (int k0 = 0; k0 < K; k0 += 64) {
    const size_t kb = (size_t)k0 * 2;        // half0 byte offset (R8-native)
    // half 0 (verbatim R8 staging)
    load_lds16(Asrc0 + kb, lAd);
    load_lds16(Asrc1 + kb, lAd + 1024);
    load_lds16(Bsrc0 + kb, lBd);
    load_lds16(Bsrc1 + kb, lBd + 1024);
    // half 1 (same expressions, +64 bytes = +32 bf16, into the "2" tiles)
    load_lds16(Asrc0 + kb + 64, lA2d);
    load_lds16(Asrc1 + kb + 64, lA2d + 1024);
    load_lds16(Bsrc0 + kb + 64, lB2d);
    load_lds16(Bsrc1 + kb + 64, lB2d + 1024);
    SCHED0;              // pin all 8 DMA issues before the barrier
    __syncthreads();     // vmcnt(0)+lgkmcnt(0)+barrier: both halves landed

    // half 0 (verbatim R8 reads + MFMA)
    {
      bf16x8 af[4], bfv[4];
#pragma unroll
      for (int mi = 0; mi < 4; mi++)
        af[mi] = *reinterpret_cast<const bf16x8*>(&lA[(wm + mi * 16 + fr) * 32 + fq * 8]);
#pragma unroll
      for (int ni = 0; ni < 4; ni++)
        bfv[ni] = *reinterpret_cast<const bf16x8*>(&lB[(wn + ni * 16 + fr) * 32 + fq * 8]);
      __builtin_amdgcn_s_setprio(1);
#pragma unroll
      for (int mi = 0; mi < 4; mi++)
#pragma unroll
        for (int ni = 0; ni < 4; ni++)
          acc[mi][ni] = __builtin_amdgcn_mfma_f32_16x16x32_bf16(af[mi], bfv[ni], acc[mi][ni], 0, 0, 0);
      __builtin_amdgcn_s_setprio(0);
    }
    // half 1
    {
      bf16x8 af[4], bfv[4];
#pragma unroll
      for (int mi = 0; mi < 4; mi++)
        af[mi] = *reinterpret_cast<const bf16x8*>(&lA2[(wm + mi * 16 + fr) * 32 + fq * 8]);
#pragma unroll
      for (int ni = 0; ni < 4; ni++)
        bfv[ni] = *reinterpret_cast<const bf16x8*>(&lB2[(wn + ni * 16 + fr) * 32 + fq * 8]);
      __builtin_amdgcn_s_setprio(1);
#pragma unroll
      for (int mi = 0; mi < 4; mi++)
#pragma unroll
        for (int ni = 0; ni < 4; ni++)
          acc[mi][ni] = __builtin_amdgcn_mfma_f32_16x16x32_bf16(af[mi], bfv[ni], acc[mi][ni], 0, 0, 0);
      __builtin_amdgcn_s_setprio(0);
    }
    SCHED0;              // block next-iter DMA from hoisting above this barrier
    __syncthreads();     // all reads serviced before next stage overwrites
  }

  // epilogue (verbatim R8)
#pragma unroll
  for (int mi = 0; mi < 4; mi++) {
#pragma unroll
    for (int r = 0; r < 4; r++) {
      int row = row0 + wm + mi * 16 + fq * 4 + r;
      OutT* Cp = C + (size_t)row * N + col0 + wn + fr;
#pragma unroll
      for (int ni = 0; ni < 4; ni++) store_out(Cp + ni * 16, acc[mi][ni][r]);
    }
  }
}

// ---------------- RoPE (in place, strided), folds score scale into Q ----------------
__global__ void rope_kernel(bf16_t* __restrict__ x, int heads, int rstride, float scale) {
  int idx = blockIdx.x * blockDim.x + threadIdx.x;  // total = S*heads*64
  int i = idx & 63;
  int h = (idx >> 6) % heads;
  int s = idx / (64 * heads);
  const float NEG_LOG1E4_64 = -0.14391156f;  // -ln(10000)/64
  float freq = __expf((float)i * NEG_LOG1E4_64);
  float ang = (float)s * freq;
  float sn, cs;
  __sincosf(ang, &sn, &cs);
  bf16_t* p = x + (size_t)s * rstride + h * DH;
  float x1 = bf2f(p[i]);
  float x2 = bf2f(p[i + 64]);
  p[i]      = f2bf((x1 * cs - x2 * sn) * scale);
  p[i + 64] = f2bf((x2 * cs + x1 * sn) * scale);
}

// ---------------- transpose [R][C] -> [C][R] (bf16), strided input ----------------
__global__ void transpose_kernel(const bf16_t* __restrict__ in, bf16_t* __restrict__ out,
                                 int R, int C, int in_rstride) {
  __shared__ bf16_t tile[64][65];
  int c0 = blockIdx.x * 64, r0 = blockIdx.y * 64;
  int t = threadIdx.x;
#pragma unroll
  for (int i = 0; i < 16; i++) {
    int idx = t + i * 256;
    int r = idx >> 6, c = idx & 63;
    tile[r][c] = in[(size_t)(r0 + r) * in_rstride + c0 + c];
  }
  __syncthreads();
#pragma unroll
  for (int i = 0; i < 16; i++) {
    int idx = t + i * 256;
    int r = idx >> 6, c = idx & 63;
    out[(size_t)(c0 + r) * R + r0 + c] = tile[c][r];
  }
}

// ---------------- flash attention (causal, GQA) ----------------
// grid (16, NH): workgroup p handles Q-blocks {31-p, p} -> exactly 33 KV-tiles
// each (perfect balance; 512 blocks = 2/CU, all resident). 256 threads = 4 waves.
// KVBLK=64, K+V double-buffered LDS, one barrier/tile; XOR-swizzle slot^=(row&15)
// via pre-swizzled global source. P roundtrip via lP[16][72].
__global__ __launch_bounds__(256)
void attn_kernel(const bf16_t* __restrict__ Qkv, const bf16_t* __restrict__ Vt,
                 bf16_t* __restrict__ O) {
  __shared__ __align__(16) char lK[2][64 * 256];   // 16 KB x2
  __shared__ __align__(16) char lV[2][64 * 256];   // 16 KB x2
  __shared__ __align__(16) bf16_t lP[4][16 * 72];  // 9216 B

  const int t = threadIdx.x, lane = t & 63, wave = t >> 6;
  const int h = blockIdx.y, kvh = h >> 2;
  const int pid = blockIdx.x;                      // 0..15
  const int fr = lane & 15, fq = lane >> 4;

  // ---- staging constants (per-thread) ----
  const int gc = wave * 4 + (lane >> 4);
  const int sS = (lane & 15) ^ (gc & 15);
  const char* KsrcB = (const char*)(Qkv + HD + (size_t)kvh * DH) +
                      (size_t)gc * QKV_STRIDE_B + sS * 16;
  const int dVc = gc * 2 + (sS >> 3);
  const char* VsrcB = (const char*)Vt + (size_t)kvh * DH * S_LEN * 2 +
                      (size_t)dVc * 4096 + (sS & 7) * 16;
  char* dKw = (char*)lK[0] + wave * 1024;
  char* dVw = (char*)lV[0] + wave * 1024;

  auto stage = [&](int buf, int kv0) {
    char* dk = dKw + buf * (64 * 256);
    char* dv = dVw + buf * (64 * 256);
    const char* ks = KsrcB + (size_t)kv0 * QKV_STRIDE_B;
    const char* vs = VsrcB + (size_t)kv0 * 2;
#pragma unroll
    for (int i = 0; i < 4; i++) {
      load_lds16(ks + i * (16 * QKV_STRIDE_B), dk + i * 4096);
      load_lds16(vs + i * (size_t)(32 * 4096), dv + i * 4096);
    }
  };

  stage(0, 0);
  int buf = 0;

  for (int pass = 0; pass < 2; pass++) {
    const int qb = pass ? pid : (31 - pid);        // long block first
    const int q0 = qb * 64 + wave * 16;

    // Q fragments for this pass
    bf16x8 qf[4];
    const bf16_t* Qp = Qkv + (size_t)(q0 + fr) * NQKV + h * DH + fq * 8;
#pragma unroll
    for (int kt = 0; kt < 4; kt++)
      qf[kt] = *reinterpret_cast<const bf16x8*>(Qp + kt * 32);

    f32x4 o_acc[8] = {};
    float m_run[4] = {-1e30f, -1e30f, -1e30f, -1e30f};
    float l_run[4] = {0.f, 0.f, 0.f, 0.f};

    for (int tt = 0; tt <= qb; tt++) {
      __syncthreads();  // implicit vmcnt(0): prefetch landed; prev compute done
      if (tt < qb)            stage(buf ^ 1, (tt + 1) * 64);
      else if (pass == 0)     stage(buf ^ 1, 0);   // pass-B tile 0

      const char* cK = lK[buf];
      const char* cV = lV[buf];
      const bool diag = (tt == qb);

      // ---- S = Q K^T : 16 MFMA ----
      f32x4 s_acc[4] = {};
      __builtin_amdgcn_s_setprio(1);
#pragma unroll
      for (int nt = 0; nt < 4; nt++) {
        const char* rowp = cK + (nt * 16 + fr) * 256;
#pragma unroll
        for (int kt = 0; kt < 4; kt++) {
          const bf16x8 kf = *reinterpret_cast<const bf16x8*>(
              rowp + (((kt * 4 + fq) ^ fr) << 4));
          s_acc[nt] = __builtin_amdgcn_mfma_f32_16x16x32_bf16(qf[kt], kf, s_acc[nt], 0, 0, 0);
        }
      }
      __builtin_amdgcn_s_setprio(0);

      // ---- online softmax, defer-max (THR=8) ----
      float pmax[4];
#pragma unroll
      for (int r = 0; r < 4; r++) {
        if (diag) {
          const int qrel = wave * 16 + fq * 4 + r;
#pragma unroll
          for (int nt = 0; nt < 4; nt++)
            if (nt * 16 + fr > qrel) s_acc[nt][r] = -1e30f;
        }
        float mr = fmaxf(fmaxf(s_acc[0][r], s_acc[1][r]), fmaxf(s_acc[2][r], s_acc[3][r]));
#pragma unroll
        for (int off = 1; off < 16; off <<= 1) mr = fmaxf(mr, __shfl_xor(mr, off, 16));
        pmax[r] = mr;
      }
      bool nb = (pmax[0] > m_run[0] + 8.f) || (pmax[1] > m_run[1] + 8.f) ||
                (pmax[2] > m_run[2] + 8.f) || (pmax[3] > m_run[3] + 8.f);
      if (__any(nb)) {
#pragma unroll
        for (int r = 0; r < 4; r++) {
          float mnew = fmaxf(m_run[r], pmax[r]);
          float alpha = __expf(m_run[r] - mnew);
#pragma unroll
          for (int ni = 0; ni < 8; ni++) o_acc[ni][r] *= alpha;
          l_run[r] *= alpha;
          m_run[r] = mnew;
        }
      }
      bf16_t* lPw = lP[wave];
#pragma unroll
      for (int r = 0; r < 4; r++) {
        float p0 = __expf(s_acc[0][r] - m_run[r]);
        float p1 = __expf(s_acc[1][r] - m_run[r]);
        float p2 = __expf(s_acc[2][r] - m_run[r]);
        float p3 = __expf(s_acc[3][r] - m_run[r]);
        float sr = (p0 + p1) + (p2 + p3);
#pragma unroll
        for (int off = 1; off < 16; off <<= 1) sr += __shfl_xor(sr, off, 16);
        l_run[r] += sr;
        const int row = fq * 4 + r;
        lPw[row * 72 + fr]      = f2bf(p0);
        lPw[row * 72 + 16 + fr] = f2bf(p1);
        lPw[row * 72 + 32 + fr] = f2bf(p2);
        lPw[row * 72 + 48 + fr] = f2bf(p3);
      }

      // ---- O += P V : 16 MFMA ----
#pragma unroll
      for (int kk = 0; kk < 2; kk++) {
        const bf16x8 pf = *reinterpret_cast<const bf16x8*>(lPw + fr * 72 + kk * 32 + fq * 8);
        __builtin_amdgcn_s_setprio(1);
#pragma unroll
        for (int ni = 0; ni < 8; ni++) {
          const int d = ni * 16 + fr;
          const int g = d >> 1;
          const int slot = ((d & 1) * 8 + kk * 4 + fq) ^ (g & 15);
          const bf16x8 vf = *reinterpret_cast<const bf16x8*>(cV + g * 256 + (slot << 4));
          o_acc[ni] = __builtin_amdgcn_mfma_f32_16x16x32_bf16(pf, vf, o_acc[ni], 0, 0, 0);
        }
        __builtin_amdgcn_s_setprio(0);
      }
      buf ^= 1;
    }

    // ---- epilogue: normalize and store this pass's rows ----
#pragma unroll
    for (int r = 0; r < 4; r++) {
      int qrow = q0 + fq * 4 + r;
      float inv = 1.0f / l_run[r];
      bf16_t* Op = O + ((size_t)qrow * NH + h) * DH + fr;
#pragma unroll
      for (int ni = 0; ni < 8; ni++) Op[ni * 16] = f2bf(o_acc[ni][r] * inv);
    }
  }
}

// ---------------- launch ----------------
extern "C" void kernel_launch(void* const* d_in, const int* in_sizes, int n_in,
                              void* d_out, int out_size, void* d_ws, size_t ws_size,
                              hipStream_t stream) {
  const float* X  = (const float*)d_in[0];
  const float* Wq = (const float*)d_in[1];
  const float* Wk = (const float*)d_in[2];
  const float* Wv = (const float*)d_in[3];
  const float* Wo = (const float*)d_in[4];
  float* out = (float*)d_out;

  char* ws = (char*)d_ws;
  size_t off = 0;
  auto alloc = [&](size_t bytes) {
    char* p = ws + off;
    off += (bytes + 255) & ~(size_t)255;
    return p;
  };
  const size_t kvdim = (size_t)NKV * DH;           // 1024
  bf16_t* Xb    = (bf16_t*)alloc((size_t)S_LEN * HD * 2);
  bf16_t* Wqkvb = (bf16_t*)alloc((size_t)NQKV * HD * 2);   // [6144][4096]
  bf16_t* Wob   = (bf16_t*)alloc((size_t)HD * HD * 2);
  bf16_t* QKVb  = (bf16_t*)alloc((size_t)S_LEN * NQKV * 2);  // [2048][6144]
  bf16_t* Vtb   = (bf16_t*)alloc((size_t)S_LEN * kvdim * 2); // [1024][2048]
  bf16_t* AOb   = (bf16_t*)alloc((size_t)S_LEN * HD * 2);
  (void)ws_size;

  auto cvt = [&](const float* in, bf16_t* o, size_t n) {
    int n8 = (int)(n / 8);
    int blocks = (n8 + 255) / 256;
    if (blocks > 2048) blocks = 2048;
    cvt_kernel<<<dim3(blocks), dim3(256), 0, stream>>>(in, o, n8);
  };
  cvt(X,  Xb,    (size_t)S_LEN * HD);
  cvt(Wq, Wqkvb, (size_t)HD * HD);
  cvt(Wk, Wqkvb + (size_t)HD * HD,   kvdim * HD);
  cvt(Wv, Wqkvb + (size_t)(HD + kvdim) * HD, kvdim * HD);
  cvt(Wo, Wob,   (size_t)HD * HD);

  // fused QKV projection: [2048][6144]
  {
    int nbx = NQKV / 128, nby = S_LEN / 128;
    gemm_bt32x2_kernel<bf16_t><<<dim3(nbx * nby), dim3(256), 0, stream>>>(
        Xb, Wqkvb, QKVb, S_LEN, NQKV, HD, nbx);
  }

  // RoPE (scale 1/sqrt(128) folded into Q); K slice at col 4096
  rope_kernel<<<dim3(S_LEN * NH * 64 / 256), dim3(256), 0, stream>>>(
      QKVb, NH, NQKV, 0.08838834764831845f);
  rope_kernel<<<dim3(S_LEN * NKV * 64 / 256), dim3(256), 0, stream>>>(
      QKVb + HD, NKV, NQKV, 1.0f);

  // V^T ([1024][2048]) from V slice at col 5120
  transpose_kernel<<<dim3((int)kvdim / 64, S_LEN / 64), dim3(256), 0, stream>>>(
      QKVb + HD + kvdim, Vtb, S_LEN, (int)kvdim, NQKV);

  // attention (paired causal blocks: perfect balance)
  attn_kernel<<<dim3(16, NH), dim3(256), 0, stream>>>(QKVb, Vtb, AOb);

  // output projection (f32 out)
  {
    int nbx = HD / 128, nby = S_LEN / 128;
    gemm_bt32x2_kernel<float><<<dim3(nbx * nby), dim3(256), 0, stream>>>(
        AOb, Wob, out, S_LEN, HD, HD, nbx);
  }
}